// Round 10
// baseline (499.669 us; speedup 1.0000x reference)
//
#include <hip/hip_runtime.h>
#include <hip/hip_bf16.h>

#define NF 128
#define EF 32
#define CF 3
#define H  512
#define EB 32   // edges per block (edge_kernel tile)

typedef __attribute__((ext_vector_type(8))) short bf16x8;
typedef __attribute__((ext_vector_type(4))) float f32x4;

// branch-free CELU: max(x, exp(min(x,0))-1)
__device__ __forceinline__ float celu_f(float x) {
    return fmaxf(x, __expf(fminf(x, 0.0f)) - 1.0f);
}
// HW packed f32->bf16 (RNE), 1 instruction for 2 values
__device__ __forceinline__ uint cvtpk(float lo, float hi) {
    uint r;
    asm("v_cvt_pk_bf16_f32 %0, %1, %2" : "=v"(r) : "v"(lo), "v"(hi));
    return r;
}
__device__ __forceinline__ bf16x8 pack8(float4 v0, float4 v1) {
    union { uint4 u; bf16x8 b; } r;
    r.u.x = cvtpk(v0.x, v0.y); r.u.y = cvtpk(v0.z, v0.w);
    r.u.z = cvtpk(v1.x, v1.y); r.u.w = cvtpk(v1.z, v1.w);
    return r.b;
}
__device__ __forceinline__ float b2f(ushort s) {
    union { uint u; float f; } v; v.u = ((uint)s) << 16; return v.f;
}
__device__ __forceinline__ void unpack4(uint2 v, float* o) {
    union { uint u; float f; } x;
    x.u = v.x << 16;          o[0] = x.f;
    x.u = v.x & 0xffff0000u;  o[1] = x.f;
    x.u = v.y << 16;          o[2] = x.f;
    x.u = v.y & 0xffff0000u;  o[3] = x.f;
}

// ---------------- sort-by-dst machinery ----------------
__global__ void hist_kernel(const int* __restrict__ dst, int* __restrict__ cnt, int n_edges) {
    int i = blockIdx.x * 256 + threadIdx.x;
    if (i < n_edges) atomicAdd(&cnt[dst[i]], 1);
}

__global__ void scan_kernel(int* __restrict__ cnt, int n_nodes) {
    __shared__ int part[1024];
    const int t = threadIdx.x;
    const int per = (n_nodes + 1023) / 1024;
    int s = 0;
    for (int i = 0; i < per; ++i) {
        int idx = t * per + i;
        if (idx < n_nodes) s += cnt[idx];
    }
    part[t] = s;
    __syncthreads();
    for (int off = 1; off < 1024; off <<= 1) {
        int v = (t >= off) ? part[t - off] : 0;
        __syncthreads();
        part[t] += v;
        __syncthreads();
    }
    int acc = part[t] - s;
    for (int i = 0; i < per; ++i) {
        int idx = t * per + i;
        if (idx < n_nodes) {
            int c = cnt[idx];
            cnt[idx] = acc;
            acc += c;
        }
    }
}

__global__ void scatter_kernel(const int* __restrict__ dst, int* __restrict__ cursor,
                               int* __restrict__ perm, int n_edges) {
    int i = blockIdx.x * 256 + threadIdx.x;
    if (i < n_edges) {
        int pos = atomicAdd(&cursor[dst[i]], 1);
        perm[pos] = i;
    }
}

// prep: bf16-transposed weights.
__global__ void prep_kernel(const float* __restrict__ We, const float* __restrict__ Weo,
                            const float* __restrict__ Wn, const float* __restrict__ Wn1,
                            const float* __restrict__ Wn2,
                            ushort* __restrict__ Wet, ushort* __restrict__ Weot,
                            ushort* __restrict__ Wnt, ushort* __restrict__ Wn1t,
                            ushort* __restrict__ Wn2t) {
    int i = blockIdx.x * 256 + threadIdx.x;
    if (i < H * EF) {
        int j = i / EF, k = i % EF;
        Wet[i] = (ushort)cvtpk(We[(size_t)k * H + j], 0.f);
        int o = i / H, j2 = i % H;
        Weot[i] = (ushort)cvtpk(Weo[(size_t)j2 * EF + o], 0.f);
    }
    if (i < H * NF) {
        int o = i >> 7, k = i & 127;
        Wnt[i] = (ushort)cvtpk(Wn[(size_t)k * H + o], 0.f);
        int o2 = i >> 9, k2 = i & 511;
        Wn2t[i] = (ushort)cvtpk(Wn2[(size_t)k2 * NF + o2], 0.f);
    }
    if (i < H * H) {
        int o = i >> 9, k = i & 511;
        Wn1t[i] = (ushort)cvtpk(Wn1[(size_t)k * H + o], 0.f);
    }
}

// Kernel 1 (MFMA, swapped operands).
// hc layout: per node, 128 groups of 16B: [h(4g..4g+1)|h(4g+2..4g+3)|c(4g..4g+1)|c(4g+2..4g+3)]
__global__ __launch_bounds__(256) void node_expand_kernel(
        const float* __restrict__ hfeats, const float* __restrict__ cfeats,
        const ushort* __restrict__ Wnt, const float* __restrict__ bn,
        const float* __restrict__ Wc, const float* __restrict__ bc,
        ushort* __restrict__ hc, int n_nodes) {
    __shared__ ushort hf[32 * NF];
    __shared__ float cf[32][4];
    const int t = threadIdx.x;
    const int lane = t & 63;
    const int w = t >> 6;
    const int node0 = blockIdx.x * 32;

    for (int i = t; i < 32 * 16; i += 256) {
        int row = i >> 4, g = i & 15;
        int node = node0 + row; if (node >= n_nodes) node = n_nodes - 1;
        const float* p = hfeats + (size_t)node * NF + g * 8;
        float4 v0 = *(const float4*)p;
        float4 v1 = *(const float4*)(p + 4);
        ((bf16x8*)hf)[row * 16 + (g ^ (row & 7))] = pack8(v0, v1);
    }
    for (int i = t; i < 32 * CF; i += 256) {
        int n = i / CF, k = i % CF;
        int node = node0 + n; if (node >= n_nodes) node = n_nodes - 1;
        cf[n][k] = cfeats[(size_t)node * CF + k];
    }
    __syncthreads();

    const int ar = lane & 15;
    const int hi = lane >> 4;
    const int ak = hi * 8;

    f32x4 acc[2][8];
    #pragma unroll
    for (int nt = 0; nt < 2; ++nt)
        #pragma unroll
        for (int q = 0; q < 8; ++q) { f32x4 z = {0.f,0.f,0.f,0.f}; acc[nt][q] = z; }

    for (int kstep = 0; kstep < NF / 32; ++kstep) {
        bf16x8 nfrag[2];
        #pragma unroll
        for (int nt = 0; nt < 2; ++nt) {
            int r = nt * 16 + ar;
            int g = kstep * 4 + hi;
            nfrag[nt] = ((const bf16x8*)hf)[r * 16 + (g ^ (r & 7))];
        }
        #pragma unroll
        for (int q = 0; q < 8; ++q) {
            bf16x8 wf = *(const bf16x8*)(Wnt + (size_t)((w * 8 + q) * 16 + ar) * NF + kstep * 32 + ak);
            acc[0][q] = __builtin_amdgcn_mfma_f32_16x16x32_bf16(wf, nfrag[0], acc[0][q], 0, 0, 0);
            acc[1][q] = __builtin_amdgcn_mfma_f32_16x16x32_bf16(wf, nfrag[1], acc[1][q], 0, 0, 0);
        }
    }
    #pragma unroll
    for (int q = 0; q < 8; ++q) {
        const int jbase = (w * 8 + q) * 16 + hi * 4;
        const float4 bv = *(const float4*)(bn + jbase);
        #pragma unroll
        for (int nt = 0; nt < 2; ++nt) {
            int node = node0 + nt * 16 + ar;
            if (node < n_nodes) {
                uint2 pk;
                pk.x = cvtpk(celu_f(acc[nt][q][0] + bv.x), celu_f(acc[nt][q][1] + bv.y));
                pk.y = cvtpk(celu_f(acc[nt][q][2] + bv.z), celu_f(acc[nt][q][3] + bv.w));
                *(uint2*)(hc + (size_t)node * 1024 + (jbase >> 2) * 8) = pk;
            }
        }
    }

    // coord expansion
    for (int i = t; i < 32 * 64; i += 256) {
        int n = i >> 6, gj = i & 63;
        int node = node0 + n;
        if (node < n_nodes) {
            int j = gj * 8;
            float c0 = cf[n][0], c1 = cf[n][1], c2 = cf[n][2];
            float v[8];
            #pragma unroll
            for (int u = 0; u < 8; ++u)
                v[u] = celu_f(bc[j + u] + c0 * Wc[j + u] + c1 * Wc[H + j + u] + c2 * Wc[2 * H + j + u]);
            uint2 p0, p1;
            p0.x = cvtpk(v[0], v[1]); p0.y = cvtpk(v[2], v[3]);
            p1.x = cvtpk(v[4], v[5]); p1.y = cvtpk(v[6], v[7]);
            *(uint2*)(hc + (size_t)node * 1024 + (2 * gj) * 8 + 4) = p0;
            *(uint2*)(hc + (size_t)node * 1024 + (2 * gj + 1) * 8 + 4) = p1;
        }
    }
}

// c_out kernel (reads c-halves from hc)
__global__ __launch_bounds__(256) void c_out_kernel(
        const float* __restrict__ cfeats, const ushort* __restrict__ hc,
        const float* __restrict__ Wco, const float* __restrict__ bco,
        float* __restrict__ c_out, int n_nodes) {
    const int t = threadIdx.x;
    const int lane = t & 63;
    const int w = t >> 6;
    const int node = blockIdx.x * 4 + w;
    if (node >= n_nodes) return;
    uint2 cv0 = *(const uint2*)(hc + (size_t)node * 1024 + (2 * lane) * 8 + 4);
    uint2 cv1 = *(const uint2*)(hc + (size_t)node * 1024 + (2 * lane + 1) * 8 + 4);
    float cv[8];
    unpack4(cv0, cv);
    unpack4(cv1, cv + 4);
    float a0 = 0.f, a1 = 0.f, a2 = 0.f;
    #pragma unroll
    for (int u = 0; u < 8; ++u) {
        int j = lane * 8 + u;
        a0 += cv[u] * Wco[j * CF + 0];
        a1 += cv[u] * Wco[j * CF + 1];
        a2 += cv[u] * Wco[j * CF + 2];
    }
    #pragma unroll
    for (int m = 32; m >= 1; m >>= 1) {
        a0 += __shfl_xor(a0, m);
        a1 += __shfl_xor(a1, m);
        a2 += __shfl_xor(a2, m);
    }
    if (lane < 3) {
        float s = (lane == 0) ? a0 : (lane == 1) ? a1 : a2;
        c_out[(size_t)node * CF + lane] = cfeats[(size_t)node * CF + lane] + celu_f(bco[lane] + s);
    }
}

// Kernel 2 (edge, MFMA swapped, dst-sorted, EB=32, half-buffered e512).
// Schedule: A0 | sync | B0(w0-1) ∥ C0(w2-3) | sync | A1 | sync | B1(w2-3) ∥ C1(w0-1)
// B partition = R9 (grp0: edges 0-15 on t<128; grp1: edges 16-31 on t>=128) -> same flush count.
__global__ __launch_bounds__(256) void edge_kernel(
        const float* __restrict__ efeats,
        const int* __restrict__ src, const int* __restrict__ dst,
        const int* __restrict__ perm,
        const ushort* __restrict__ Wet, const float* __restrict__ be,
        const ushort* __restrict__ Weot, const float* __restrict__ beo,
        const ushort* __restrict__ hc,
        float* __restrict__ k_acc, float* __restrict__ e_out, int n_edges) {
    __shared__ ushort e512[16 * 512];        // 16 KB (half tile)
    __shared__ int s_perm[EB], s_src[EB], s_dst[EB];
    const int t = threadIdx.x;
    const int lane = t & 63;
    const int w = t >> 6;

    const int nwg = gridDim.x;
    const int q = nwg >> 3, r = nwg & 7;
    const int xcd = blockIdx.x & 7, sub = blockIdx.x >> 3;
    const int bid = (xcd < r ? xcd * (q + 1) : r * (q + 1) + (xcd - r) * q) + sub;
    const int e0 = bid * EB;

    if (t < EB) {
        int e = e0 + t;
        int pe = (e < n_edges) ? perm[e] : -1;
        s_perm[t] = pe;
        s_src[t] = (pe >= 0) ? src[pe] : 0;
        s_dst[t] = (pe >= 0) ? dst[pe] : -1;
    }
    __syncthreads();

    const int ar = lane & 15;
    const int hi = lane >> 4;
    const int ak = hi * 8;

    // A-phase weight fragments (invariant across halves)
    bf16x8 wfrag[8];
    #pragma unroll
    for (int qq = 0; qq < 8; ++qq)
        wfrag[qq] = *(const bf16x8*)(Wet + (size_t)((w * 8 + qq) * 16 + ar) * EF + ak);

    #pragma unroll
    for (int half = 0; half < 2; ++half) {
        // ---- Phase A(half): 16 edges -> e512 ----
        bf16x8 efrag;
        {
            int pe = s_perm[half * 16 + ar];
            if (pe < 0) pe = 0;
            const float* p = efeats + (size_t)pe * EF + ak;
            float4 v0 = *(const float4*)p;
            float4 v1 = *(const float4*)(p + 4);
            efrag = pack8(v0, v1);
        }
        f32x4 acc[8];
        #pragma unroll
        for (int qq = 0; qq < 8; ++qq) { f32x4 z = {0.f,0.f,0.f,0.f}; acc[qq] = z; }
        #pragma unroll
        for (int qq = 0; qq < 8; ++qq)
            acc[qq] = __builtin_amdgcn_mfma_f32_16x16x32_bf16(wfrag[qq], efrag, acc[qq], 0, 0, 0);
        #pragma unroll
        for (int qq = 0; qq < 8; ++qq) {
            const int jbase = (w * 8 + qq) * 16 + hi * 4;
            const float4 bv = *(const float4*)(be + jbase);
            uint2 pk;
            pk.x = cvtpk(celu_f(acc[qq][0] + bv.x), celu_f(acc[qq][1] + bv.y));
            pk.y = cvtpk(celu_f(acc[qq][2] + bv.z), celu_f(acc[qq][3] + bv.w));
            const int gs = (jbase >> 3) ^ (ar & 7);
            *(uint2*)(&e512[ar * 512 + gs * 8 + (jbase & 7)]) = pk;
        }
        __syncthreads();

        // ---- Phase B(half) on its group's waves; Phase C(half) on the other waves ----
        if ((t >> 7) == half) {
            // B: this thread's group owns edges [half*16, half*16+16)
            const int ct = t & 127;
            const int j0 = ct * 4;
            const int g = j0 >> 3, go = j0 & 7;
            float a_[4];
            a_[0] = a_[1] = a_[2] = a_[3] = 0.f;
            int cur = -1;
            #pragma unroll
            for (int i = 0; i < 16; ++i) {
                const int e = half * 16 + i;
                const int d = __builtin_amdgcn_readfirstlane(s_dst[e]);
                const int dc = (d < 0) ? 0 : d;
                const int s_ = s_src[e];
                uint4 sv = *(const uint4*)(hc + (size_t)s_ * 1024 + ct * 8);
                uint2 cdv = *(const uint2*)(hc + (size_t)dc * 1024 + ct * 8 + 4);
                uint2 ev = *(const uint2*)(&e512[i * 512 + (g ^ (i & 7)) * 8 + go]);
                if (d != cur) {
                    if (cur >= 0) {
                        #pragma unroll
                        for (int u = 0; u < 4; ++u)
                            atomicAdd(&k_acc[(size_t)cur * H + j0 + u], a_[u]);
                        a_[0] = a_[1] = a_[2] = a_[3] = 0.f;
                    }
                    cur = d;
                }
                if (d >= 0) {
                    float hs_[4], cs_[4], cd_[4], ev_[4];
                    uint2 hv; hv.x = sv.x; hv.y = sv.y;
                    uint2 cv; cv.x = sv.z; cv.y = sv.w;
                    unpack4(hv, hs_);
                    unpack4(cv, cs_);
                    unpack4(cdv, cd_);
                    unpack4(ev, ev_);
                    #pragma unroll
                    for (int u = 0; u < 4; ++u)
                        a_[u] += fabsf(cd_[u] - cs_[u]) * (hs_[u] * ev_[u]);
                }
            }
            if (cur >= 0) {
                #pragma unroll
                for (int u = 0; u < 4; ++u)
                    atomicAdd(&k_acc[(size_t)cur * H + j0 + u], a_[u]);
            }
        } else {
            // C: e_out for this half's 16 edges; ot = w&1 covers 32 out-chans
            const int ot = w & 1;
            f32x4 accc = {0.f, 0.f, 0.f, 0.f};
            #pragma unroll
            for (int kt = 0; kt < 16; ++kt) {
                bf16x8 wfC = *(const bf16x8*)(Weot + (size_t)(ot * 16 + ar) * H + kt * 32 + ak);
                const int gs = (kt * 4 + hi) ^ (ar & 7);
                bf16x8 b = *(const bf16x8*)(&e512[ar * 512 + gs * 8]);
                accc = __builtin_amdgcn_mfma_f32_16x16x32_bf16(wfC, b, accc, 0, 0, 0);
            }
            const int pe = s_perm[half * 16 + ar];
            if (pe >= 0) {
                const int obase = ot * 16 + hi * 4;
                const float4 bo = *(const float4*)(beo + obase);
                size_t idx = (size_t)pe * EF + obase;
                float4 ef4 = *(const float4*)(efeats + idx);
                float4 o;
                o.x = ef4.x + celu_f(accc[0] + bo.x);
                o.y = ef4.y + celu_f(accc[1] + bo.y);
                o.z = ef4.z + celu_f(accc[2] + bo.z);
                o.w = ef4.w + celu_f(accc[3] + bo.w);
                *(float4*)(e_out + idx) = o;
            }
        }
        __syncthreads();
    }
}

// Kernel 3 (MFMA swapped): h_out = hfeats + celu(celu(k@Wn1+bn1)@Wn2+bn2)
__global__ __launch_bounds__(256) void node_out_kernel(
        const float* __restrict__ hfeats, const float* __restrict__ k_acc,
        const ushort* __restrict__ Wn1t, const float* __restrict__ bn1,
        const ushort* __restrict__ Wn2t, const float* __restrict__ bn2,
        float* __restrict__ h_out, int n_nodes) {
    __shared__ ushort kt_s[32 * H];
    const int t = threadIdx.x;
    const int lane = t & 63;
    const int w = t >> 6;
    const int node0 = blockIdx.x * 32;

    for (int i = t; i < 32 * 64; i += 256) {
        int row = i >> 6, g = i & 63;
        int node = node0 + row; if (node >= n_nodes) node = n_nodes - 1;
        const float* p = k_acc + (size_t)node * H + g * 8;
        float4 v0 = *(const float4*)p;
        float4 v1 = *(const float4*)(p + 4);
        ((bf16x8*)kt_s)[row * 64 + (g ^ (row & 7))] = pack8(v0, v1);
    }
    __syncthreads();

    const int ar = lane & 15;
    const int hi = lane >> 4;
    const int ak = hi * 8;

    f32x4 acc[2][8];
    #pragma unroll
    for (int nt = 0; nt < 2; ++nt)
        #pragma unroll
        for (int q = 0; q < 8; ++q) { f32x4 z = {0.f,0.f,0.f,0.f}; acc[nt][q] = z; }

    for (int kstep = 0; kstep < H / 32; ++kstep) {
        bf16x8 kfrag[2];
        #pragma unroll
        for (int nt = 0; nt < 2; ++nt) {
            int rr = nt * 16 + ar;
            int g = kstep * 4 + hi;
            kfrag[nt] = ((const bf16x8*)kt_s)[rr * 64 + (g ^ (rr & 7))];
        }
        #pragma unroll
        for (int q = 0; q < 8; ++q) {
            bf16x8 wf = *(const bf16x8*)(Wn1t + (size_t)((w * 8 + q) * 16 + ar) * H + kstep * 32 + ak);
            acc[0][q] = __builtin_amdgcn_mfma_f32_16x16x32_bf16(wf, kfrag[0], acc[0][q], 0, 0, 0);
            acc[1][q] = __builtin_amdgcn_mfma_f32_16x16x32_bf16(wf, kfrag[1], acc[1][q], 0, 0, 0);
        }
    }
    __syncthreads();

    #pragma unroll
    for (int q = 0; q < 8; ++q) {
        const int jbase = (w * 8 + q) * 16 + hi * 4;
        const float4 bv = *(const float4*)(bn1 + jbase);
        #pragma unroll
        for (int nt = 0; nt < 2; ++nt) {
            const int rr = nt * 16 + ar;
            uint2 pk;
            pk.x = cvtpk(celu_f(acc[nt][q][0] + bv.x), celu_f(acc[nt][q][1] + bv.y));
            pk.y = cvtpk(celu_f(acc[nt][q][2] + bv.z), celu_f(acc[nt][q][3] + bv.w));
            const int gs = (jbase >> 3) ^ (rr & 7);
            *(uint2*)(&kt_s[rr * 512 + gs * 8 + (jbase & 7)]) = pk;
        }
    }
    __syncthreads();

    f32x4 acc2[2][2];
    #pragma unroll
    for (int nt = 0; nt < 2; ++nt)
        #pragma unroll
        for (int ct = 0; ct < 2; ++ct) { f32x4 z = {0.f,0.f,0.f,0.f}; acc2[nt][ct] = z; }

    for (int kstep = 0; kstep < H / 32; ++kstep) {
        bf16x8 tfrag[2];
        #pragma unroll
        for (int nt = 0; nt < 2; ++nt) {
            int rr = nt * 16 + ar;
            int g = kstep * 4 + hi;
            tfrag[nt] = ((const bf16x8*)kt_s)[rr * 64 + (g ^ (rr & 7))];
        }
        #pragma unroll
        for (int ct = 0; ct < 2; ++ct) {
            bf16x8 wf = *(const bf16x8*)(Wn2t + (size_t)((w * 2 + ct) * 16 + ar) * H + kstep * 32 + ak);
            acc2[0][ct] = __builtin_amdgcn_mfma_f32_16x16x32_bf16(wf, tfrag[0], acc2[0][ct], 0, 0, 0);
            acc2[1][ct] = __builtin_amdgcn_mfma_f32_16x16x32_bf16(wf, tfrag[1], acc2[1][ct], 0, 0, 0);
        }
    }
    #pragma unroll
    for (int ct = 0; ct < 2; ++ct) {
        const int jbase = (w * 2 + ct) * 16 + hi * 4;
        const float4 bv = *(const float4*)(bn2 + jbase);
        #pragma unroll
        for (int nt = 0; nt < 2; ++nt) {
            const int node = node0 + nt * 16 + ar;
            if (node < n_nodes) {
                size_t idx = (size_t)node * NF + jbase;
                float4 hf4 = *(const float4*)(hfeats + idx);
                float4 o;
                o.x = hf4.x + celu_f(acc2[nt][ct][0] + bv.x);
                o.y = hf4.y + celu_f(acc2[nt][ct][1] + bv.y);
                o.z = hf4.z + celu_f(acc2[nt][ct][2] + bv.z);
                o.w = hf4.w + celu_f(acc2[nt][ct][3] + bv.w);
                *(float4*)(h_out + idx) = o;
            }
        }
    }
}

extern "C" void kernel_launch(void* const* d_in, const int* in_sizes, int n_in,
                              void* d_out, int out_size, void* d_ws, size_t ws_size,
                              hipStream_t stream) {
    const float* hfeats = (const float*)d_in[0];
    const float* cfeats = (const float*)d_in[1];
    const float* efeats = (const float*)d_in[2];
    const int*   src    = (const int*)d_in[3];
    const int*   dst    = (const int*)d_in[4];
    const float* Wn  = (const float*)d_in[5];  const float* bn  = (const float*)d_in[6];
    const float* We  = (const float*)d_in[7];  const float* be  = (const float*)d_in[8];
    const float* Wc  = (const float*)d_in[9];  const float* bc  = (const float*)d_in[10];
    const float* Wn1 = (const float*)d_in[11]; const float* bn1 = (const float*)d_in[12];
    const float* Wn2 = (const float*)d_in[13]; const float* bn2 = (const float*)d_in[14];
    const float* Weo = (const float*)d_in[15]; const float* beo = (const float*)d_in[16];
    const float* Wco = (const float*)d_in[17]; const float* bco = (const float*)d_in[18];

    const int n_nodes = in_sizes[0] / NF;
    const int n_edges = in_sizes[2] / EF;

    float*  k_buf = (float*)d_ws;                                   // [N,H] f32
    ushort* hc    = (ushort*)(k_buf + (size_t)n_nodes * H);         // [N,2H] bf16 interleaved
    ushort* Wet   = hc + (size_t)n_nodes * H * 2;                   // [H,EF]
    ushort* Weot  = Wet + (size_t)H * EF;                           // [EF,H]
    ushort* Wnt   = Weot + (size_t)H * EF;                          // [H,NF]
    ushort* Wn1t  = Wnt + (size_t)H * NF;                           // [H,H]
    ushort* Wn2t  = Wn1t + (size_t)H * H;                           // [NF,H]
    int*    cnt   = (int*)(Wn2t + (size_t)NF * H);                  // [N]
    int*    perm  = cnt + n_nodes;                                  // [E]

    float* h_out = (float*)d_out;
    float* c_out = h_out + (size_t)n_nodes * NF;
    float* e_out = c_out + (size_t)n_nodes * CF;

    hipMemsetAsync(k_buf, 0, (size_t)n_nodes * H * sizeof(float), stream);
    hipMemsetAsync(cnt, 0, (size_t)n_nodes * sizeof(int), stream);

    prep_kernel<<<(H * H + 255) / 256, 256, 0, stream>>>(
        We, Weo, Wn, Wn1, Wn2, Wet, Weot, Wnt, Wn1t, Wn2t);
    hist_kernel<<<(n_edges + 255) / 256, 256, 0, stream>>>(dst, cnt, n_edges);
    scan_kernel<<<1, 1024, 0, stream>>>(cnt, n_nodes);
    scatter_kernel<<<(n_edges + 255) / 256, 256, 0, stream>>>(dst, cnt, perm, n_edges);

    node_expand_kernel<<<(n_nodes + 31) / 32, 256, 0, stream>>>(
        hfeats, cfeats, Wnt, bn, Wc, bc, hc, n_nodes);

    c_out_kernel<<<(n_nodes + 3) / 4, 256, 0, stream>>>(
        cfeats, hc, Wco, bco, c_out, n_nodes);

    edge_kernel<<<(n_edges + EB - 1) / EB, 256, 0, stream>>>(
        efeats, src, dst, perm, Wet, be, Weot, beo, hc, k_buf, e_out, n_edges);

    node_out_kernel<<<(n_nodes + 31) / 32, 256, 0, stream>>>(
        hfeats, k_buf, Wn1t, bn1, Wn2t, bn2, h_out, n_nodes);
}

// Round 11
// 485.406 us; speedup vs baseline: 1.0294x; 1.0294x over previous
//
#include <hip/hip_runtime.h>
#include <hip/hip_bf16.h>

#define NF 128
#define EF 32
#define CF 3
#define H  512
#define EB 32   // edges per block (edge_kernel tile)

typedef __attribute__((ext_vector_type(8))) short bf16x8;
typedef __attribute__((ext_vector_type(4))) float f32x4;

// branch-free CELU: max(x, exp(min(x,0))-1)
__device__ __forceinline__ float celu_f(float x) {
    return fmaxf(x, __expf(fminf(x, 0.0f)) - 1.0f);
}
// HW packed f32->bf16 (RNE), 1 instruction for 2 values
__device__ __forceinline__ uint cvtpk(float lo, float hi) {
    uint r;
    asm("v_cvt_pk_bf16_f32 %0, %1, %2" : "=v"(r) : "v"(lo), "v"(hi));
    return r;
}
__device__ __forceinline__ bf16x8 pack8(float4 v0, float4 v1) {
    union { uint4 u; bf16x8 b; } r;
    r.u.x = cvtpk(v0.x, v0.y); r.u.y = cvtpk(v0.z, v0.w);
    r.u.z = cvtpk(v1.x, v1.y); r.u.w = cvtpk(v1.z, v1.w);
    return r.b;
}
__device__ __forceinline__ float b2f(ushort s) {
    union { uint u; float f; } v; v.u = ((uint)s) << 16; return v.f;
}
__device__ __forceinline__ void unpack4(uint2 v, float* o) {
    union { uint u; float f; } x;
    x.u = v.x << 16;          o[0] = x.f;
    x.u = v.x & 0xffff0000u;  o[1] = x.f;
    x.u = v.y << 16;          o[2] = x.f;
    x.u = v.y & 0xffff0000u;  o[3] = x.f;
}

// ---------------- sort-by-dst machinery ----------------
__global__ void hist_kernel(const int* __restrict__ dst, int* __restrict__ cnt, int n_edges) {
    int i = blockIdx.x * 256 + threadIdx.x;
    if (i < n_edges) atomicAdd(&cnt[dst[i]], 1);
}

__global__ void scan_kernel(int* __restrict__ cnt, int n_nodes) {
    __shared__ int part[1024];
    const int t = threadIdx.x;
    const int per = (n_nodes + 1023) / 1024;
    int s = 0;
    for (int i = 0; i < per; ++i) {
        int idx = t * per + i;
        if (idx < n_nodes) s += cnt[idx];
    }
    part[t] = s;
    __syncthreads();
    for (int off = 1; off < 1024; off <<= 1) {
        int v = (t >= off) ? part[t - off] : 0;
        __syncthreads();
        part[t] += v;
        __syncthreads();
    }
    int acc = part[t] - s;
    for (int i = 0; i < per; ++i) {
        int idx = t * per + i;
        if (idx < n_nodes) {
            int c = cnt[idx];
            cnt[idx] = acc;
            acc += c;
        }
    }
}

__global__ void scatter_kernel(const int* __restrict__ dst, int* __restrict__ cursor,
                               int* __restrict__ perm, int n_edges) {
    int i = blockIdx.x * 256 + threadIdx.x;
    if (i < n_edges) {
        int pos = atomicAdd(&cursor[dst[i]], 1);
        perm[pos] = i;
    }
}

// prep: bf16-transposed weights.
__global__ void prep_kernel(const float* __restrict__ We, const float* __restrict__ Weo,
                            const float* __restrict__ Wn, const float* __restrict__ Wn1,
                            const float* __restrict__ Wn2,
                            ushort* __restrict__ Wet, ushort* __restrict__ Weot,
                            ushort* __restrict__ Wnt, ushort* __restrict__ Wn1t,
                            ushort* __restrict__ Wn2t) {
    int i = blockIdx.x * 256 + threadIdx.x;
    if (i < H * EF) {
        int j = i / EF, k = i % EF;
        Wet[i] = (ushort)cvtpk(We[(size_t)k * H + j], 0.f);
        int o = i / H, j2 = i % H;
        Weot[i] = (ushort)cvtpk(Weo[(size_t)j2 * EF + o], 0.f);
    }
    if (i < H * NF) {
        int o = i >> 7, k = i & 127;
        Wnt[i] = (ushort)cvtpk(Wn[(size_t)k * H + o], 0.f);
        int o2 = i >> 9, k2 = i & 511;
        Wn2t[i] = (ushort)cvtpk(Wn2[(size_t)k2 * NF + o2], 0.f);
    }
    if (i < H * H) {
        int o = i >> 9, k = i & 511;
        Wn1t[i] = (ushort)cvtpk(Wn1[(size_t)k * H + o], 0.f);
    }
}

// Kernel 1 (MFMA, swapped operands).
// hc layout: per node, 128 groups of 16B: [h(4g..4g+1)|h(4g+2..4g+3)|c(4g..4g+1)|c(4g+2..4g+3)]
__global__ __launch_bounds__(256) void node_expand_kernel(
        const float* __restrict__ hfeats, const float* __restrict__ cfeats,
        const ushort* __restrict__ Wnt, const float* __restrict__ bn,
        const float* __restrict__ Wc, const float* __restrict__ bc,
        ushort* __restrict__ hc, int n_nodes) {
    __shared__ ushort hf[32 * NF];
    __shared__ float cf[32][4];
    const int t = threadIdx.x;
    const int lane = t & 63;
    const int w = t >> 6;
    const int node0 = blockIdx.x * 32;

    for (int i = t; i < 32 * 16; i += 256) {
        int row = i >> 4, g = i & 15;
        int node = node0 + row; if (node >= n_nodes) node = n_nodes - 1;
        const float* p = hfeats + (size_t)node * NF + g * 8;
        float4 v0 = *(const float4*)p;
        float4 v1 = *(const float4*)(p + 4);
        ((bf16x8*)hf)[row * 16 + (g ^ (row & 7))] = pack8(v0, v1);
    }
    for (int i = t; i < 32 * CF; i += 256) {
        int n = i / CF, k = i % CF;
        int node = node0 + n; if (node >= n_nodes) node = n_nodes - 1;
        cf[n][k] = cfeats[(size_t)node * CF + k];
    }
    __syncthreads();

    const int ar = lane & 15;
    const int hi = lane >> 4;
    const int ak = hi * 8;

    f32x4 acc[2][8];
    #pragma unroll
    for (int nt = 0; nt < 2; ++nt)
        #pragma unroll
        for (int q = 0; q < 8; ++q) { f32x4 z = {0.f,0.f,0.f,0.f}; acc[nt][q] = z; }

    for (int kstep = 0; kstep < NF / 32; ++kstep) {
        bf16x8 nfrag[2];
        #pragma unroll
        for (int nt = 0; nt < 2; ++nt) {
            int r = nt * 16 + ar;
            int g = kstep * 4 + hi;
            nfrag[nt] = ((const bf16x8*)hf)[r * 16 + (g ^ (r & 7))];
        }
        #pragma unroll
        for (int q = 0; q < 8; ++q) {
            bf16x8 wf = *(const bf16x8*)(Wnt + (size_t)((w * 8 + q) * 16 + ar) * NF + kstep * 32 + ak);
            acc[0][q] = __builtin_amdgcn_mfma_f32_16x16x32_bf16(wf, nfrag[0], acc[0][q], 0, 0, 0);
            acc[1][q] = __builtin_amdgcn_mfma_f32_16x16x32_bf16(wf, nfrag[1], acc[1][q], 0, 0, 0);
        }
    }
    #pragma unroll
    for (int q = 0; q < 8; ++q) {
        const int jbase = (w * 8 + q) * 16 + hi * 4;
        const float4 bv = *(const float4*)(bn + jbase);
        #pragma unroll
        for (int nt = 0; nt < 2; ++nt) {
            int node = node0 + nt * 16 + ar;
            if (node < n_nodes) {
                uint2 pk;
                pk.x = cvtpk(celu_f(acc[nt][q][0] + bv.x), celu_f(acc[nt][q][1] + bv.y));
                pk.y = cvtpk(celu_f(acc[nt][q][2] + bv.z), celu_f(acc[nt][q][3] + bv.w));
                *(uint2*)(hc + (size_t)node * 1024 + (jbase >> 2) * 8) = pk;
            }
        }
    }

    // coord expansion
    for (int i = t; i < 32 * 64; i += 256) {
        int n = i >> 6, gj = i & 63;
        int node = node0 + n;
        if (node < n_nodes) {
            int j = gj * 8;
            float c0 = cf[n][0], c1 = cf[n][1], c2 = cf[n][2];
            float v[8];
            #pragma unroll
            for (int u = 0; u < 8; ++u)
                v[u] = celu_f(bc[j + u] + c0 * Wc[j + u] + c1 * Wc[H + j + u] + c2 * Wc[2 * H + j + u]);
            uint2 p0, p1;
            p0.x = cvtpk(v[0], v[1]); p0.y = cvtpk(v[2], v[3]);
            p1.x = cvtpk(v[4], v[5]); p1.y = cvtpk(v[6], v[7]);
            *(uint2*)(hc + (size_t)node * 1024 + (2 * gj) * 8 + 4) = p0;
            *(uint2*)(hc + (size_t)node * 1024 + (2 * gj + 1) * 8 + 4) = p1;
        }
    }
}

// c_out kernel (reads c-halves from hc)
__global__ __launch_bounds__(256) void c_out_kernel(
        const float* __restrict__ cfeats, const ushort* __restrict__ hc,
        const float* __restrict__ Wco, const float* __restrict__ bco,
        float* __restrict__ c_out, int n_nodes) {
    const int t = threadIdx.x;
    const int lane = t & 63;
    const int w = t >> 6;
    const int node = blockIdx.x * 4 + w;
    if (node >= n_nodes) return;
    uint2 cv0 = *(const uint2*)(hc + (size_t)node * 1024 + (2 * lane) * 8 + 4);
    uint2 cv1 = *(const uint2*)(hc + (size_t)node * 1024 + (2 * lane + 1) * 8 + 4);
    float cv[8];
    unpack4(cv0, cv);
    unpack4(cv1, cv + 4);
    float a0 = 0.f, a1 = 0.f, a2 = 0.f;
    #pragma unroll
    for (int u = 0; u < 8; ++u) {
        int j = lane * 8 + u;
        a0 += cv[u] * Wco[j * CF + 0];
        a1 += cv[u] * Wco[j * CF + 1];
        a2 += cv[u] * Wco[j * CF + 2];
    }
    #pragma unroll
    for (int m = 32; m >= 1; m >>= 1) {
        a0 += __shfl_xor(a0, m);
        a1 += __shfl_xor(a1, m);
        a2 += __shfl_xor(a2, m);
    }
    if (lane < 3) {
        float s = (lane == 0) ? a0 : (lane == 1) ? a1 : a2;
        c_out[(size_t)node * CF + lane] = cfeats[(size_t)node * CF + lane] + celu_f(bco[lane] + s);
    }
}

// Kernel 2 (edge, MFMA swapped, dst-sorted, EB=32, 512-thread block).
// A on all 8 waves | sync | B on waves 0-3 (R9 partition: 2 grp x 16 edges, 4 cols/thread)
//                          ∥ C on waves 4-7 (2 edge-tiles x 2 out-tiles)
__global__ __launch_bounds__(512, 8) void edge_kernel(
        const float* __restrict__ efeats,
        const int* __restrict__ src, const int* __restrict__ dst,
        const int* __restrict__ perm,
        const ushort* __restrict__ Wet, const float* __restrict__ be,
        const ushort* __restrict__ Weot, const float* __restrict__ beo,
        const ushort* __restrict__ hc,
        float* __restrict__ k_acc, float* __restrict__ e_out, int n_edges) {
    __shared__ ushort e512[EB * 512];        // 32 KB
    __shared__ int s_perm[EB], s_src[EB], s_dst[EB];
    const int t = threadIdx.x;
    const int lane = t & 63;
    const int w = t >> 6;              // 0..7

    const int nwg = gridDim.x;
    const int q = nwg >> 3, r = nwg & 7;
    const int xcd = blockIdx.x & 7, sub = blockIdx.x >> 3;
    const int bid = (xcd < r ? xcd * (q + 1) : r * (q + 1) + (xcd - r) * q) + sub;
    const int e0 = bid * EB;

    if (t < EB) {
        int e = e0 + t;
        int pe = (e < n_edges) ? perm[e] : -1;
        s_perm[t] = pe;
        s_src[t] = (pe >= 0) ? src[pe] : 0;
        s_dst[t] = (pe >= 0) ? dst[pe] : -1;
    }
    __syncthreads();

    const int ar = lane & 15;
    const int hi = lane >> 4;
    const int ak = hi * 8;

    // ---- Phase A (8 waves, 4 q-tiles each): e512 = celu(ef @ We + be) ----
    {
        bf16x8 wfrag[4];
        #pragma unroll
        for (int qq = 0; qq < 4; ++qq)
            wfrag[qq] = *(const bf16x8*)(Wet + (size_t)((w * 4 + qq) * 16 + ar) * EF + ak);
        #pragma unroll
        for (int et = 0; et < 2; ++et) {
            bf16x8 efrag;
            {
                int pe = s_perm[et * 16 + ar];
                if (pe < 0) pe = 0;
                const float* p = efeats + (size_t)pe * EF + ak;
                float4 v0 = *(const float4*)p;
                float4 v1 = *(const float4*)(p + 4);
                efrag = pack8(v0, v1);
            }
            f32x4 acc[4];
            #pragma unroll
            for (int qq = 0; qq < 4; ++qq) { f32x4 z = {0.f,0.f,0.f,0.f}; acc[qq] = z; }
            #pragma unroll
            for (int qq = 0; qq < 4; ++qq)
                acc[qq] = __builtin_amdgcn_mfma_f32_16x16x32_bf16(wfrag[qq], efrag, acc[qq], 0, 0, 0);
            const int e_l = et * 16 + ar;
            #pragma unroll
            for (int qq = 0; qq < 4; ++qq) {
                const int jbase = (w * 4 + qq) * 16 + hi * 4;
                const float4 bv = *(const float4*)(be + jbase);
                uint2 pk;
                pk.x = cvtpk(celu_f(acc[qq][0] + bv.x), celu_f(acc[qq][1] + bv.y));
                pk.y = cvtpk(celu_f(acc[qq][2] + bv.z), celu_f(acc[qq][3] + bv.w));
                const int gs = (jbase >> 3) ^ (e_l & 7);
                *(uint2*)(&e512[e_l * 512 + gs * 8 + (jbase & 7)]) = pk;
            }
        }
    }
    __syncthreads();

    if (w < 4) {
        // ---- Phase B (waves 0-3): 2 grp x 16 edges; 4 cols/thread ----
        const int grp = t >> 7;            // 0: edges 0-15, 1: edges 16-31
        const int ct = t & 127;
        const int j0 = ct * 4;
        const int g = j0 >> 3, go = j0 & 7;
        float a_[4];
        a_[0] = a_[1] = a_[2] = a_[3] = 0.f;
        int cur = -1;
        #pragma unroll
        for (int i = 0; i < 16; ++i) {
            const int e = grp * 16 + i;
            const int d = __builtin_amdgcn_readfirstlane(s_dst[e]);
            const int dc = (d < 0) ? 0 : d;
            const int s_ = s_src[e];
            uint4 sv = *(const uint4*)(hc + (size_t)s_ * 1024 + ct * 8);
            uint2 cdv = *(const uint2*)(hc + (size_t)dc * 1024 + ct * 8 + 4);
            uint2 ev = *(const uint2*)(&e512[e * 512 + (g ^ (e & 7)) * 8 + go]);
            if (d != cur) {
                if (cur >= 0) {
                    #pragma unroll
                    for (int u = 0; u < 4; ++u)
                        atomicAdd(&k_acc[(size_t)cur * H + j0 + u], a_[u]);
                    a_[0] = a_[1] = a_[2] = a_[3] = 0.f;
                }
                cur = d;
            }
            if (d >= 0) {
                float hs_[4], cs_[4], cd_[4], ev_[4];
                uint2 hv; hv.x = sv.x; hv.y = sv.y;
                uint2 cv; cv.x = sv.z; cv.y = sv.w;
                unpack4(hv, hs_);
                unpack4(cv, cs_);
                unpack4(cdv, cd_);
                unpack4(ev, ev_);
                #pragma unroll
                for (int u = 0; u < 4; ++u)
                    a_[u] += fabsf(cd_[u] - cs_[u]) * (hs_[u] * ev_[u]);
            }
        }
        if (cur >= 0) {
            #pragma unroll
            for (int u = 0; u < 4; ++u)
                atomicAdd(&k_acc[(size_t)cur * H + j0 + u], a_[u]);
        }
    } else {
        // ---- Phase C (waves 4-7): e_out = efeats + celu(e512 @ Weo + beo) ----
        const int wc = w - 4;
        const int ot = wc & 1, et = wc >> 1;
        const int e_l = et * 16 + ar;
        f32x4 accc = {0.f, 0.f, 0.f, 0.f};
        #pragma unroll
        for (int kt = 0; kt < 16; ++kt) {
            bf16x8 wfC = *(const bf16x8*)(Weot + (size_t)(ot * 16 + ar) * H + kt * 32 + ak);
            const int gs = (kt * 4 + hi) ^ (e_l & 7);
            bf16x8 b = *(const bf16x8*)(&e512[e_l * 512 + gs * 8]);
            accc = __builtin_amdgcn_mfma_f32_16x16x32_bf16(wfC, b, accc, 0, 0, 0);
        }
        const int pe = s_perm[e_l];
        if (pe >= 0) {
            const int obase = ot * 16 + hi * 4;
            const float4 bo = *(const float4*)(beo + obase);
            size_t idx = (size_t)pe * EF + obase;
            float4 ef4 = *(const float4*)(efeats + idx);
            float4 o;
            o.x = ef4.x + celu_f(accc[0] + bo.x);
            o.y = ef4.y + celu_f(accc[1] + bo.y);
            o.z = ef4.z + celu_f(accc[2] + bo.z);
            o.w = ef4.w + celu_f(accc[3] + bo.w);
            *(float4*)(e_out + idx) = o;
        }
    }
}

// Kernel 3 (MFMA swapped): h_out = hfeats + celu(celu(k@Wn1+bn1)@Wn2+bn2)
__global__ __launch_bounds__(256) void node_out_kernel(
        const float* __restrict__ hfeats, const float* __restrict__ k_acc,
        const ushort* __restrict__ Wn1t, const float* __restrict__ bn1,
        const ushort* __restrict__ Wn2t, const float* __restrict__ bn2,
        float* __restrict__ h_out, int n_nodes) {
    __shared__ ushort kt_s[32 * H];
    const int t = threadIdx.x;
    const int lane = t & 63;
    const int w = t >> 6;
    const int node0 = blockIdx.x * 32;

    for (int i = t; i < 32 * 64; i += 256) {
        int row = i >> 6, g = i & 63;
        int node = node0 + row; if (node >= n_nodes) node = n_nodes - 1;
        const float* p = k_acc + (size_t)node * H + g * 8;
        float4 v0 = *(const float4*)p;
        float4 v1 = *(const float4*)(p + 4);
        ((bf16x8*)kt_s)[row * 64 + (g ^ (row & 7))] = pack8(v0, v1);
    }
    __syncthreads();

    const int ar = lane & 15;
    const int hi = lane >> 4;
    const int ak = hi * 8;

    f32x4 acc[2][8];
    #pragma unroll
    for (int nt = 0; nt < 2; ++nt)
        #pragma unroll
        for (int q = 0; q < 8; ++q) { f32x4 z = {0.f,0.f,0.f,0.f}; acc[nt][q] = z; }

    for (int kstep = 0; kstep < H / 32; ++kstep) {
        bf16x8 kfrag[2];
        #pragma unroll
        for (int nt = 0; nt < 2; ++nt) {
            int rr = nt * 16 + ar;
            int g = kstep * 4 + hi;
            kfrag[nt] = ((const bf16x8*)kt_s)[rr * 64 + (g ^ (rr & 7))];
        }
        #pragma unroll
        for (int q = 0; q < 8; ++q) {
            bf16x8 wf = *(const bf16x8*)(Wn1t + (size_t)((w * 8 + q) * 16 + ar) * H + kstep * 32 + ak);
            acc[0][q] = __builtin_amdgcn_mfma_f32_16x16x32_bf16(wf, kfrag[0], acc[0][q], 0, 0, 0);
            acc[1][q] = __builtin_amdgcn_mfma_f32_16x16x32_bf16(wf, kfrag[1], acc[1][q], 0, 0, 0);
        }
    }
    __syncthreads();

    #pragma unroll
    for (int q = 0; q < 8; ++q) {
        const int jbase = (w * 8 + q) * 16 + hi * 4;
        const float4 bv = *(const float4*)(bn1 + jbase);
        #pragma unroll
        for (int nt = 0; nt < 2; ++nt) {
            const int rr = nt * 16 + ar;
            uint2 pk;
            pk.x = cvtpk(celu_f(acc[nt][q][0] + bv.x), celu_f(acc[nt][q][1] + bv.y));
            pk.y = cvtpk(celu_f(acc[nt][q][2] + bv.z), celu_f(acc[nt][q][3] + bv.w));
            const int gs = (jbase >> 3) ^ (rr & 7);
            *(uint2*)(&kt_s[rr * 512 + gs * 8 + (jbase & 7)]) = pk;
        }
    }
    __syncthreads();

    f32x4 acc2[2][2];
    #pragma unroll
    for (int nt = 0; nt < 2; ++nt)
        #pragma unroll
        for (int ct = 0; ct < 2; ++ct) { f32x4 z = {0.f,0.f,0.f,0.f}; acc2[nt][ct] = z; }

    for (int kstep = 0; kstep < H / 32; ++kstep) {
        bf16x8 tfrag[2];
        #pragma unroll
        for (int nt = 0; nt < 2; ++nt) {
            int rr = nt * 16 + ar;
            int g = kstep * 4 + hi;
            tfrag[nt] = ((const bf16x8*)kt_s)[rr * 64 + (g ^ (rr & 7))];
        }
        #pragma unroll
        for (int ct = 0; ct < 2; ++ct) {
            bf16x8 wf = *(const bf16x8*)(Wn2t + (size_t)((w * 2 + ct) * 16 + ar) * H + kstep * 32 + ak);
            acc2[0][ct] = __builtin_amdgcn_mfma_f32_16x16x32_bf16(wf, tfrag[0], acc2[0][ct], 0, 0, 0);
            acc2[1][ct] = __builtin_amdgcn_mfma_f32_16x16x32_bf16(wf, tfrag[1], acc2[1][ct], 0, 0, 0);
        }
    }
    #pragma unroll
    for (int ct = 0; ct < 2; ++ct) {
        const int jbase = (w * 2 + ct) * 16 + hi * 4;
        const float4 bv = *(const float4*)(bn2 + jbase);
        #pragma unroll
        for (int nt = 0; nt < 2; ++nt) {
            const int node = node0 + nt * 16 + ar;
            if (node < n_nodes) {
                size_t idx = (size_t)node * NF + jbase;
                float4 hf4 = *(const float4*)(hfeats + idx);
                float4 o;
                o.x = hf4.x + celu_f(acc2[nt][ct][0] + bv.x);
                o.y = hf4.y + celu_f(acc2[nt][ct][1] + bv.y);
                o.z = hf4.z + celu_f(acc2[nt][ct][2] + bv.z);
                o.w = hf4.w + celu_f(acc2[nt][ct][3] + bv.w);
                *(float4*)(h_out + idx) = o;
            }
        }
    }
}

extern "C" void kernel_launch(void* const* d_in, const int* in_sizes, int n_in,
                              void* d_out, int out_size, void* d_ws, size_t ws_size,
                              hipStream_t stream) {
    const float* hfeats = (const float*)d_in[0];
    const float* cfeats = (const float*)d_in[1];
    const float* efeats = (const float*)d_in[2];
    const int*   src    = (const int*)d_in[3];
    const int*   dst    = (const int*)d_in[4];
    const float* Wn  = (const float*)d_in[5];  const float* bn  = (const float*)d_in[6];
    const float* We  = (const float*)d_in[7];  const float* be  = (const float*)d_in[8];
    const float* Wc  = (const float*)d_in[9];  const float* bc  = (const float*)d_in[10];
    const float* Wn1 = (const float*)d_in[11]; const float* bn1 = (const float*)d_in[12];
    const float* Wn2 = (const float*)d_in[13]; const float* bn2 = (const float*)d_in[14];
    const float* Weo = (const float*)d_in[15]; const float* beo = (const float*)d_in[16];
    const float* Wco = (const float*)d_in[17]; const float* bco = (const float*)d_in[18];

    const int n_nodes = in_sizes[0] / NF;
    const int n_edges = in_sizes[2] / EF;

    float*  k_buf = (float*)d_ws;                                   // [N,H] f32
    ushort* hc    = (ushort*)(k_buf + (size_t)n_nodes * H);         // [N,2H] bf16 interleaved
    ushort* Wet   = hc + (size_t)n_nodes * H * 2;                   // [H,EF]
    ushort* Weot  = Wet + (size_t)H * EF;                           // [EF,H]
    ushort* Wnt   = Weot + (size_t)H * EF;                          // [H,NF]
    ushort* Wn1t  = Wnt + (size_t)H * NF;                           // [H,H]
    ushort* Wn2t  = Wn1t + (size_t)H * H;                           // [NF,H]
    int*    cnt   = (int*)(Wn2t + (size_t)NF * H);                  // [N]
    int*    perm  = cnt + n_nodes;                                  // [E]

    float* h_out = (float*)d_out;
    float* c_out = h_out + (size_t)n_nodes * NF;
    float* e_out = c_out + (size_t)n_nodes * CF;

    hipMemsetAsync(k_buf, 0, (size_t)n_nodes * H * sizeof(float), stream);
    hipMemsetAsync(cnt, 0, (size_t)n_nodes * sizeof(int), stream);

    prep_kernel<<<(H * H + 255) / 256, 256, 0, stream>>>(
        We, Weo, Wn, Wn1, Wn2, Wet, Weot, Wnt, Wn1t, Wn2t);
    hist_kernel<<<(n_edges + 255) / 256, 256, 0, stream>>>(dst, cnt, n_edges);
    scan_kernel<<<1, 1024, 0, stream>>>(cnt, n_nodes);
    scatter_kernel<<<(n_edges + 255) / 256, 256, 0, stream>>>(dst, cnt, perm, n_edges);

    node_expand_kernel<<<(n_nodes + 31) / 32, 256, 0, stream>>>(
        hfeats, cfeats, Wnt, bn, Wc, bc, hc, n_nodes);

    c_out_kernel<<<(n_nodes + 3) / 4, 256, 0, stream>>>(
        cfeats, hc, Wco, bco, c_out, n_nodes);

    edge_kernel<<<(n_edges + EB - 1) / EB, 512, 0, stream>>>(
        efeats, src, dst, perm, Wet, be, Weot, beo, hc, k_buf, e_out, n_edges);

    node_out_kernel<<<(n_nodes + 31) / 32, 256, 0, stream>>>(
        hfeats, k_buf, Wn1t, bn1, Wn2t, bn2, h_out, n_nodes);
}

// Round 12
// 459.821 us; speedup vs baseline: 1.0867x; 1.0556x over previous
//
#include <hip/hip_runtime.h>
#include <hip/hip_bf16.h>

#define NF 128
#define EF 32
#define CF 3
#define H  512
#define EB 32   // edges per block (edge_kernel tile)

typedef __attribute__((ext_vector_type(8))) short bf16x8;
typedef __attribute__((ext_vector_type(4))) float f32x4;

// branch-free CELU: max(x, exp(min(x,0))-1)
__device__ __forceinline__ float celu_f(float x) {
    return fmaxf(x, __expf(fminf(x, 0.0f)) - 1.0f);
}
// HW packed f32->bf16 (RNE), 1 instruction for 2 values
__device__ __forceinline__ uint cvtpk(float lo, float hi) {
    uint r;
    asm("v_cvt_pk_bf16_f32 %0, %1, %2" : "=v"(r) : "v"(lo), "v"(hi));
    return r;
}
__device__ __forceinline__ bf16x8 pack8(float4 v0, float4 v1) {
    union { uint4 u; bf16x8 b; } r;
    r.u.x = cvtpk(v0.x, v0.y); r.u.y = cvtpk(v0.z, v0.w);
    r.u.z = cvtpk(v1.x, v1.y); r.u.w = cvtpk(v1.z, v1.w);
    return r.b;
}
__device__ __forceinline__ float b2f(ushort s) {
    union { uint u; float f; } v; v.u = ((uint)s) << 16; return v.f;
}
__device__ __forceinline__ void unpack4(uint2 v, float* o) {
    union { uint u; float f; } x;
    x.u = v.x << 16;          o[0] = x.f;
    x.u = v.x & 0xffff0000u;  o[1] = x.f;
    x.u = v.y << 16;          o[2] = x.f;
    x.u = v.y & 0xffff0000u;  o[3] = x.f;
}

// ---------------- sort-by-dst machinery ----------------
__global__ void hist_kernel(const int* __restrict__ dst, int* __restrict__ cnt, int n_edges) {
    int i = blockIdx.x * 256 + threadIdx.x;
    if (i < n_edges) atomicAdd(&cnt[dst[i]], 1);
}

__global__ void scan_kernel(int* __restrict__ cnt, int n_nodes) {
    __shared__ int part[1024];
    const int t = threadIdx.x;
    const int per = (n_nodes + 1023) / 1024;
    int s = 0;
    for (int i = 0; i < per; ++i) {
        int idx = t * per + i;
        if (idx < n_nodes) s += cnt[idx];
    }
    part[t] = s;
    __syncthreads();
    for (int off = 1; off < 1024; off <<= 1) {
        int v = (t >= off) ? part[t - off] : 0;
        __syncthreads();
        part[t] += v;
        __syncthreads();
    }
    int acc = part[t] - s;
    for (int i = 0; i < per; ++i) {
        int idx = t * per + i;
        if (idx < n_nodes) {
            int c = cnt[idx];
            cnt[idx] = acc;
            acc += c;
        }
    }
}

__global__ void scatter_kernel(const int* __restrict__ dst, int* __restrict__ cursor,
                               int* __restrict__ perm, int n_edges) {
    int i = blockIdx.x * 256 + threadIdx.x;
    if (i < n_edges) {
        int pos = atomicAdd(&cursor[dst[i]], 1);
        perm[pos] = i;
    }
}

// prep: bf16-transposed weights.
__global__ void prep_kernel(const float* __restrict__ We, const float* __restrict__ Weo,
                            const float* __restrict__ Wn, const float* __restrict__ Wn1,
                            const float* __restrict__ Wn2,
                            ushort* __restrict__ Wet, ushort* __restrict__ Weot,
                            ushort* __restrict__ Wnt, ushort* __restrict__ Wn1t,
                            ushort* __restrict__ Wn2t) {
    int i = blockIdx.x * 256 + threadIdx.x;
    if (i < H * EF) {
        int j = i / EF, k = i % EF;
        Wet[i] = (ushort)cvtpk(We[(size_t)k * H + j], 0.f);
        int o = i / H, j2 = i % H;
        Weot[i] = (ushort)cvtpk(Weo[(size_t)j2 * EF + o], 0.f);
    }
    if (i < H * NF) {
        int o = i >> 7, k = i & 127;
        Wnt[i] = (ushort)cvtpk(Wn[(size_t)k * H + o], 0.f);
        int o2 = i >> 9, k2 = i & 511;
        Wn2t[i] = (ushort)cvtpk(Wn2[(size_t)k2 * NF + o2], 0.f);
    }
    if (i < H * H) {
        int o = i >> 9, k = i & 511;
        Wn1t[i] = (ushort)cvtpk(Wn1[(size_t)k * H + o], 0.f);
    }
}

// Kernel 1 (MFMA, swapped operands).
// hc layout: per node, 128 groups of 16B: [h(4g..4g+1)|h(4g+2..4g+3)|c(4g..4g+1)|c(4g+2..4g+3)]
__global__ __launch_bounds__(256) void node_expand_kernel(
        const float* __restrict__ hfeats, const float* __restrict__ cfeats,
        const ushort* __restrict__ Wnt, const float* __restrict__ bn,
        const float* __restrict__ Wc, const float* __restrict__ bc,
        ushort* __restrict__ hc, int n_nodes) {
    __shared__ ushort hf[32 * NF];
    __shared__ float cf[32][4];
    const int t = threadIdx.x;
    const int lane = t & 63;
    const int w = t >> 6;
    const int node0 = blockIdx.x * 32;

    for (int i = t; i < 32 * 16; i += 256) {
        int row = i >> 4, g = i & 15;
        int node = node0 + row; if (node >= n_nodes) node = n_nodes - 1;
        const float* p = hfeats + (size_t)node * NF + g * 8;
        float4 v0 = *(const float4*)p;
        float4 v1 = *(const float4*)(p + 4);
        ((bf16x8*)hf)[row * 16 + (g ^ (row & 7))] = pack8(v0, v1);
    }
    for (int i = t; i < 32 * CF; i += 256) {
        int n = i / CF, k = i % CF;
        int node = node0 + n; if (node >= n_nodes) node = n_nodes - 1;
        cf[n][k] = cfeats[(size_t)node * CF + k];
    }
    __syncthreads();

    const int ar = lane & 15;
    const int hi = lane >> 4;
    const int ak = hi * 8;

    f32x4 acc[2][8];
    #pragma unroll
    for (int nt = 0; nt < 2; ++nt)
        #pragma unroll
        for (int q = 0; q < 8; ++q) { f32x4 z = {0.f,0.f,0.f,0.f}; acc[nt][q] = z; }

    for (int kstep = 0; kstep < NF / 32; ++kstep) {
        bf16x8 nfrag[2];
        #pragma unroll
        for (int nt = 0; nt < 2; ++nt) {
            int r = nt * 16 + ar;
            int g = kstep * 4 + hi;
            nfrag[nt] = ((const bf16x8*)hf)[r * 16 + (g ^ (r & 7))];
        }
        #pragma unroll
        for (int q = 0; q < 8; ++q) {
            bf16x8 wf = *(const bf16x8*)(Wnt + (size_t)((w * 8 + q) * 16 + ar) * NF + kstep * 32 + ak);
            acc[0][q] = __builtin_amdgcn_mfma_f32_16x16x32_bf16(wf, nfrag[0], acc[0][q], 0, 0, 0);
            acc[1][q] = __builtin_amdgcn_mfma_f32_16x16x32_bf16(wf, nfrag[1], acc[1][q], 0, 0, 0);
        }
    }
    #pragma unroll
    for (int q = 0; q < 8; ++q) {
        const int jbase = (w * 8 + q) * 16 + hi * 4;
        const float4 bv = *(const float4*)(bn + jbase);
        #pragma unroll
        for (int nt = 0; nt < 2; ++nt) {
            int node = node0 + nt * 16 + ar;
            if (node < n_nodes) {
                uint2 pk;
                pk.x = cvtpk(celu_f(acc[nt][q][0] + bv.x), celu_f(acc[nt][q][1] + bv.y));
                pk.y = cvtpk(celu_f(acc[nt][q][2] + bv.z), celu_f(acc[nt][q][3] + bv.w));
                *(uint2*)(hc + (size_t)node * 1024 + (jbase >> 2) * 8) = pk;
            }
        }
    }

    // coord expansion
    for (int i = t; i < 32 * 64; i += 256) {
        int n = i >> 6, gj = i & 63;
        int node = node0 + n;
        if (node < n_nodes) {
            int j = gj * 8;
            float c0 = cf[n][0], c1 = cf[n][1], c2 = cf[n][2];
            float v[8];
            #pragma unroll
            for (int u = 0; u < 8; ++u)
                v[u] = celu_f(bc[j + u] + c0 * Wc[j + u] + c1 * Wc[H + j + u] + c2 * Wc[2 * H + j + u]);
            uint2 p0, p1;
            p0.x = cvtpk(v[0], v[1]); p0.y = cvtpk(v[2], v[3]);
            p1.x = cvtpk(v[4], v[5]); p1.y = cvtpk(v[6], v[7]);
            *(uint2*)(hc + (size_t)node * 1024 + (2 * gj) * 8 + 4) = p0;
            *(uint2*)(hc + (size_t)node * 1024 + (2 * gj + 1) * 8 + 4) = p1;
        }
    }
}

// c_out kernel (reads c-halves from hc)
__global__ __launch_bounds__(256) void c_out_kernel(
        const float* __restrict__ cfeats, const ushort* __restrict__ hc,
        const float* __restrict__ Wco, const float* __restrict__ bco,
        float* __restrict__ c_out, int n_nodes) {
    const int t = threadIdx.x;
    const int lane = t & 63;
    const int w = t >> 6;
    const int node = blockIdx.x * 4 + w;
    if (node >= n_nodes) return;
    uint2 cv0 = *(const uint2*)(hc + (size_t)node * 1024 + (2 * lane) * 8 + 4);
    uint2 cv1 = *(const uint2*)(hc + (size_t)node * 1024 + (2 * lane + 1) * 8 + 4);
    float cv[8];
    unpack4(cv0, cv);
    unpack4(cv1, cv + 4);
    float a0 = 0.f, a1 = 0.f, a2 = 0.f;
    #pragma unroll
    for (int u = 0; u < 8; ++u) {
        int j = lane * 8 + u;
        a0 += cv[u] * Wco[j * CF + 0];
        a1 += cv[u] * Wco[j * CF + 1];
        a2 += cv[u] * Wco[j * CF + 2];
    }
    #pragma unroll
    for (int m = 32; m >= 1; m >>= 1) {
        a0 += __shfl_xor(a0, m);
        a1 += __shfl_xor(a1, m);
        a2 += __shfl_xor(a2, m);
    }
    if (lane < 3) {
        float s = (lane == 0) ? a0 : (lane == 1) ? a1 : a2;
        c_out[(size_t)node * CF + lane] = cfeats[(size_t)node * CF + lane] + celu_f(bco[lane] + s);
    }
}

// Kernel 2 (edge, MFMA swapped, dst-sorted, EB=32, 512-thread block, 4 waves/EU min).
// A on all 8 waves | sync | B on waves 0-3 (software-pipelined chunks of 4)
//                          ∥ C on waves 4-7
__global__ __launch_bounds__(512, 4) void edge_kernel(
        const float* __restrict__ efeats,
        const int* __restrict__ src, const int* __restrict__ dst,
        const int* __restrict__ perm,
        const ushort* __restrict__ Wet, const float* __restrict__ be,
        const ushort* __restrict__ Weot, const float* __restrict__ beo,
        const ushort* __restrict__ hc,
        float* __restrict__ k_acc, float* __restrict__ e_out, int n_edges) {
    __shared__ ushort e512[EB * 512];        // 32 KB
    __shared__ int s_perm[EB], s_src[EB], s_dst[EB];
    const int t = threadIdx.x;
    const int lane = t & 63;
    const int w = t >> 6;              // 0..7

    const int nwg = gridDim.x;
    const int q = nwg >> 3, r = nwg & 7;
    const int xcd = blockIdx.x & 7, sub = blockIdx.x >> 3;
    const int bid = (xcd < r ? xcd * (q + 1) : r * (q + 1) + (xcd - r) * q) + sub;
    const int e0 = bid * EB;

    if (t < EB) {
        int e = e0 + t;
        int pe = (e < n_edges) ? perm[e] : -1;
        s_perm[t] = pe;
        s_src[t] = (pe >= 0) ? src[pe] : 0;
        s_dst[t] = (pe >= 0) ? dst[pe] : -1;
    }
    __syncthreads();

    const int ar = lane & 15;
    const int hi = lane >> 4;
    const int ak = hi * 8;

    // ---- Phase A (8 waves, 4 q-tiles each): e512 = celu(ef @ We + be) ----
    {
        bf16x8 wfrag[4];
        #pragma unroll
        for (int qq = 0; qq < 4; ++qq)
            wfrag[qq] = *(const bf16x8*)(Wet + (size_t)((w * 4 + qq) * 16 + ar) * EF + ak);
        #pragma unroll
        for (int et = 0; et < 2; ++et) {
            bf16x8 efrag;
            {
                int pe = s_perm[et * 16 + ar];
                if (pe < 0) pe = 0;
                const float* p = efeats + (size_t)pe * EF + ak;
                float4 v0 = *(const float4*)p;
                float4 v1 = *(const float4*)(p + 4);
                efrag = pack8(v0, v1);
            }
            f32x4 acc[4];
            #pragma unroll
            for (int qq = 0; qq < 4; ++qq) { f32x4 z = {0.f,0.f,0.f,0.f}; acc[qq] = z; }
            #pragma unroll
            for (int qq = 0; qq < 4; ++qq)
                acc[qq] = __builtin_amdgcn_mfma_f32_16x16x32_bf16(wfrag[qq], efrag, acc[qq], 0, 0, 0);
            const int e_l = et * 16 + ar;
            #pragma unroll
            for (int qq = 0; qq < 4; ++qq) {
                const int jbase = (w * 4 + qq) * 16 + hi * 4;
                const float4 bv = *(const float4*)(be + jbase);
                uint2 pk;
                pk.x = cvtpk(celu_f(acc[qq][0] + bv.x), celu_f(acc[qq][1] + bv.y));
                pk.y = cvtpk(celu_f(acc[qq][2] + bv.z), celu_f(acc[qq][3] + bv.w));
                const int gs = (jbase >> 3) ^ (e_l & 7);
                *(uint2*)(&e512[e_l * 512 + gs * 8 + (jbase & 7)]) = pk;
            }
        }
    }
    __syncthreads();

    if (w < 4) {
        // ---- Phase B (waves 0-3): 2 grp x 16 edges; 4 cols/thread; double-buffered
        //      chunks of 4 iterations with explicit prefetch ----
        const int grp = t >> 7;            // 0: edges 0-15, 1: edges 16-31
        const int ct = t & 127;
        const int j0 = ct * 4;
        const int g = j0 >> 3, go = j0 & 7;
        const int ebase = grp * 16;
        float a_[4];
        a_[0] = a_[1] = a_[2] = a_[3] = 0.f;
        int cur = -1;

        uint4 svb[2][4];
        uint2 cdb[2][4];
        uint2 evb[2][4];

        // prefetch chunk 0 into buffer 0
        #pragma unroll
        for (int j = 0; j < 4; ++j) {
            const int e = ebase + j;
            const int s_ = s_src[e];
            int dc = s_dst[e]; dc = (dc < 0) ? 0 : dc;
            svb[0][j] = *(const uint4*)(hc + (size_t)s_ * 1024 + ct * 8);
            cdb[0][j] = *(const uint2*)(hc + (size_t)dc * 1024 + ct * 8 + 4);
            evb[0][j] = *(const uint2*)(&e512[e * 512 + (g ^ (e & 7)) * 8 + go]);
        }

        #pragma unroll
        for (int c = 0; c < 4; ++c) {
            const int cb = c & 1, nb = cb ^ 1;
            if (c < 3) {
                // prefetch chunk c+1 into the other buffer (overlaps with processing below)
                #pragma unroll
                for (int j = 0; j < 4; ++j) {
                    const int e = ebase + (c + 1) * 4 + j;
                    const int s_ = s_src[e];
                    int dc = s_dst[e]; dc = (dc < 0) ? 0 : dc;
                    svb[nb][j] = *(const uint4*)(hc + (size_t)s_ * 1024 + ct * 8);
                    cdb[nb][j] = *(const uint2*)(hc + (size_t)dc * 1024 + ct * 8 + 4);
                    evb[nb][j] = *(const uint2*)(&e512[e * 512 + (g ^ (e & 7)) * 8 + go]);
                }
            }
            // process chunk c from buffer cb
            #pragma unroll
            for (int j = 0; j < 4; ++j) {
                const int e = ebase + c * 4 + j;
                const int d = __builtin_amdgcn_readfirstlane(s_dst[e]);
                if (d != cur) {
                    if (cur >= 0) {
                        #pragma unroll
                        for (int u = 0; u < 4; ++u)
                            atomicAdd(&k_acc[(size_t)cur * H + j0 + u], a_[u]);
                        a_[0] = a_[1] = a_[2] = a_[3] = 0.f;
                    }
                    cur = d;
                }
                if (d >= 0) {
                    float hs_[4], cs_[4], cd_[4], ev_[4];
                    uint2 hv; hv.x = svb[cb][j].x; hv.y = svb[cb][j].y;
                    uint2 cv; cv.x = svb[cb][j].z; cv.y = svb[cb][j].w;
                    unpack4(hv, hs_);
                    unpack4(cv, cs_);
                    unpack4(cdb[cb][j], cd_);
                    unpack4(evb[cb][j], ev_);
                    #pragma unroll
                    for (int u = 0; u < 4; ++u)
                        a_[u] += fabsf(cd_[u] - cs_[u]) * (hs_[u] * ev_[u]);
                }
            }
        }
        if (cur >= 0) {
            #pragma unroll
            for (int u = 0; u < 4; ++u)
                atomicAdd(&k_acc[(size_t)cur * H + j0 + u], a_[u]);
        }
    } else {
        // ---- Phase C (waves 4-7): e_out = efeats + celu(e512 @ Weo + beo) ----
        const int wc = w - 4;
        const int ot = wc & 1, et = wc >> 1;
        const int e_l = et * 16 + ar;
        f32x4 accc = {0.f, 0.f, 0.f, 0.f};
        #pragma unroll
        for (int kt = 0; kt < 16; ++kt) {
            bf16x8 wfC = *(const bf16x8*)(Weot + (size_t)(ot * 16 + ar) * H + kt * 32 + ak);
            const int gs = (kt * 4 + hi) ^ (e_l & 7);
            bf16x8 b = *(const bf16x8*)(&e512[e_l * 512 + gs * 8]);
            accc = __builtin_amdgcn_mfma_f32_16x16x32_bf16(wfC, b, accc, 0, 0, 0);
        }
        const int pe = s_perm[e_l];
        if (pe >= 0) {
            const int obase = ot * 16 + hi * 4;
            const float4 bo = *(const float4*)(beo + obase);
            size_t idx = (size_t)pe * EF + obase;
            float4 ef4 = *(const float4*)(efeats + idx);
            float4 o;
            o.x = ef4.x + celu_f(accc[0] + bo.x);
            o.y = ef4.y + celu_f(accc[1] + bo.y);
            o.z = ef4.z + celu_f(accc[2] + bo.z);
            o.w = ef4.w + celu_f(accc[3] + bo.w);
            *(float4*)(e_out + idx) = o;
        }
    }
}

// Kernel 3 (MFMA swapped): h_out = hfeats + celu(celu(k@Wn1+bn1)@Wn2+bn2)
__global__ __launch_bounds__(256) void node_out_kernel(
        const float* __restrict__ hfeats, const float* __restrict__ k_acc,
        const ushort* __restrict__ Wn1t, const float* __restrict__ bn1,
        const ushort* __restrict__ Wn2t, const float* __restrict__ bn2,
        float* __restrict__ h_out, int n_nodes) {
    __shared__ ushort kt_s[32 * H];
    const int t = threadIdx.x;
    const int lane = t & 63;
    const int w = t >> 6;
    const int node0 = blockIdx.x * 32;

    for (int i = t; i < 32 * 64; i += 256) {
        int row = i >> 6, g = i & 63;
        int node = node0 + row; if (node >= n_nodes) node = n_nodes - 1;
        const float* p = k_acc + (size_t)node * H + g * 8;
        float4 v0 = *(const float4*)p;
        float4 v1 = *(const float4*)(p + 4);
        ((bf16x8*)kt_s)[row * 64 + (g ^ (row & 7))] = pack8(v0, v1);
    }
    __syncthreads();

    const int ar = lane & 15;
    const int hi = lane >> 4;
    const int ak = hi * 8;

    f32x4 acc[2][8];
    #pragma unroll
    for (int nt = 0; nt < 2; ++nt)
        #pragma unroll
        for (int q = 0; q < 8; ++q) { f32x4 z = {0.f,0.f,0.f,0.f}; acc[nt][q] = z; }

    for (int kstep = 0; kstep < H / 32; ++kstep) {
        bf16x8 kfrag[2];
        #pragma unroll
        for (int nt = 0; nt < 2; ++nt) {
            int rr = nt * 16 + ar;
            int g = kstep * 4 + hi;
            kfrag[nt] = ((const bf16x8*)kt_s)[rr * 64 + (g ^ (rr & 7))];
        }
        #pragma unroll
        for (int q = 0; q < 8; ++q) {
            bf16x8 wf = *(const bf16x8*)(Wn1t + (size_t)((w * 8 + q) * 16 + ar) * H + kstep * 32 + ak);
            acc[0][q] = __builtin_amdgcn_mfma_f32_16x16x32_bf16(wf, kfrag[0], acc[0][q], 0, 0, 0);
            acc[1][q] = __builtin_amdgcn_mfma_f32_16x16x32_bf16(wf, kfrag[1], acc[1][q], 0, 0, 0);
        }
    }
    __syncthreads();

    #pragma unroll
    for (int q = 0; q < 8; ++q) {
        const int jbase = (w * 8 + q) * 16 + hi * 4;
        const float4 bv = *(const float4*)(bn1 + jbase);
        #pragma unroll
        for (int nt = 0; nt < 2; ++nt) {
            const int rr = nt * 16 + ar;
            uint2 pk;
            pk.x = cvtpk(celu_f(acc[nt][q][0] + bv.x), celu_f(acc[nt][q][1] + bv.y));
            pk.y = cvtpk(celu_f(acc[nt][q][2] + bv.z), celu_f(acc[nt][q][3] + bv.w));
            const int gs = (jbase >> 3) ^ (rr & 7);
            *(uint2*)(&kt_s[rr * 512 + gs * 8 + (jbase & 7)]) = pk;
        }
    }
    __syncthreads();

    f32x4 acc2[2][2];
    #pragma unroll
    for (int nt = 0; nt < 2; ++nt)
        #pragma unroll
        for (int ct = 0; ct < 2; ++ct) { f32x4 z = {0.f,0.f,0.f,0.f}; acc2[nt][ct] = z; }

    for (int kstep = 0; kstep < H / 32; ++kstep) {
        bf16x8 tfrag[2];
        #pragma unroll
        for (int nt = 0; nt < 2; ++nt) {
            int rr = nt * 16 + ar;
            int g = kstep * 4 + hi;
            tfrag[nt] = ((const bf16x8*)kt_s)[rr * 64 + (g ^ (rr & 7))];
        }
        #pragma unroll
        for (int ct = 0; ct < 2; ++ct) {
            bf16x8 wf = *(const bf16x8*)(Wn2t + (size_t)((w * 2 + ct) * 16 + ar) * H + kstep * 32 + ak);
            acc2[0][ct] = __builtin_amdgcn_mfma_f32_16x16x32_bf16(wf, tfrag[0], acc2[0][ct], 0, 0, 0);
            acc2[1][ct] = __builtin_amdgcn_mfma_f32_16x16x32_bf16(wf, tfrag[1], acc2[1][ct], 0, 0, 0);
        }
    }
    #pragma unroll
    for (int ct = 0; ct < 2; ++ct) {
        const int jbase = (w * 2 + ct) * 16 + hi * 4;
        const float4 bv = *(const float4*)(bn2 + jbase);
        #pragma unroll
        for (int nt = 0; nt < 2; ++nt) {
            const int node = node0 + nt * 16 + ar;
            if (node < n_nodes) {
                size_t idx = (size_t)node * NF + jbase;
                float4 hf4 = *(const float4*)(hfeats + idx);
                float4 o;
                o.x = hf4.x + celu_f(acc2[nt][ct][0] + bv.x);
                o.y = hf4.y + celu_f(acc2[nt][ct][1] + bv.y);
                o.z = hf4.z + celu_f(acc2[nt][ct][2] + bv.z);
                o.w = hf4.w + celu_f(acc2[nt][ct][3] + bv.w);
                *(float4*)(h_out + idx) = o;
            }
        }
    }
}

extern "C" void kernel_launch(void* const* d_in, const int* in_sizes, int n_in,
                              void* d_out, int out_size, void* d_ws, size_t ws_size,
                              hipStream_t stream) {
    const float* hfeats = (const float*)d_in[0];
    const float* cfeats = (const float*)d_in[1];
    const float* efeats = (const float*)d_in[2];
    const int*   src    = (const int*)d_in[3];
    const int*   dst    = (const int*)d_in[4];
    const float* Wn  = (const float*)d_in[5];  const float* bn  = (const float*)d_in[6];
    const float* We  = (const float*)d_in[7];  const float* be  = (const float*)d_in[8];
    const float* Wc  = (const float*)d_in[9];  const float* bc  = (const float*)d_in[10];
    const float* Wn1 = (const float*)d_in[11]; const float* bn1 = (const float*)d_in[12];
    const float* Wn2 = (const float*)d_in[13]; const float* bn2 = (const float*)d_in[14];
    const float* Weo = (const float*)d_in[15]; const float* beo = (const float*)d_in[16];
    const float* Wco = (const float*)d_in[17]; const float* bco = (const float*)d_in[18];

    const int n_nodes = in_sizes[0] / NF;
    const int n_edges = in_sizes[2] / EF;

    float*  k_buf = (float*)d_ws;                                   // [N,H] f32
    ushort* hc    = (ushort*)(k_buf + (size_t)n_nodes * H);         // [N,2H] bf16 interleaved
    ushort* Wet   = hc + (size_t)n_nodes * H * 2;                   // [H,EF]
    ushort* Weot  = Wet + (size_t)H * EF;                           // [EF,H]
    ushort* Wnt   = Weot + (size_t)H * EF;                          // [H,NF]
    ushort* Wn1t  = Wnt + (size_t)H * NF;                           // [H,H]
    ushort* Wn2t  = Wn1t + (size_t)H * H;                           // [NF,H]
    int*    cnt   = (int*)(Wn2t + (size_t)NF * H);                  // [N]
    int*    perm  = cnt + n_nodes;                                  // [E]

    float* h_out = (float*)d_out;
    float* c_out = h_out + (size_t)n_nodes * NF;
    float* e_out = c_out + (size_t)n_nodes * CF;

    hipMemsetAsync(k_buf, 0, (size_t)n_nodes * H * sizeof(float), stream);
    hipMemsetAsync(cnt, 0, (size_t)n_nodes * sizeof(int), stream);

    prep_kernel<<<(H * H + 255) / 256, 256, 0, stream>>>(
        We, Weo, Wn, Wn1, Wn2, Wet, Weot, Wnt, Wn1t, Wn2t);
    hist_kernel<<<(n_edges + 255) / 256, 256, 0, stream>>>(dst, cnt, n_edges);
    scan_kernel<<<1, 1024, 0, stream>>>(cnt, n_nodes);
    scatter_kernel<<<(n_edges + 255) / 256, 256, 0, stream>>>(dst, cnt, perm, n_edges);

    node_expand_kernel<<<(n_nodes + 31) / 32, 256, 0, stream>>>(
        hfeats, cfeats, Wnt, bn, Wc, bc, hc, n_nodes);

    c_out_kernel<<<(n_nodes + 3) / 4, 256, 0, stream>>>(
        cfeats, hc, Wco, bco, c_out, n_nodes);

    edge_kernel<<<(n_edges + EB - 1) / EB, 512, 0, stream>>>(
        efeats, src, dst, perm, Wet, be, Weot, beo, hc, k_buf, e_out, n_edges);

    node_out_kernel<<<(n_nodes + 31) / 32, 256, 0, stream>>>(
        hfeats, k_buf, Wn1t, bn1, Wn2t, bn2, h_out, n_nodes);
}

// Round 13
// 439.632 us; speedup vs baseline: 1.1366x; 1.0459x over previous
//
#include <hip/hip_runtime.h>
#include <hip/hip_bf16.h>

#define NF 128
#define EF 32
#define CF 3
#define H  512
#define EB 32   // edges per block (edge_kernel tile)

typedef __attribute__((ext_vector_type(8))) short bf16x8;
typedef __attribute__((ext_vector_type(4))) float f32x4;

// branch-free CELU: max(x, exp(min(x,0))-1)
__device__ __forceinline__ float celu_f(float x) {
    return fmaxf(x, __expf(fminf(x, 0.0f)) - 1.0f);
}
// HW packed f32->bf16 (RNE), 1 instruction for 2 values
__device__ __forceinline__ uint cvtpk(float lo, float hi) {
    uint r;
    asm("v_cvt_pk_bf16_f32 %0, %1, %2" : "=v"(r) : "v"(lo), "v"(hi));
    return r;
}
__device__ __forceinline__ bf16x8 pack8(float4 v0, float4 v1) {
    union { uint4 u; bf16x8 b; } r;
    r.u.x = cvtpk(v0.x, v0.y); r.u.y = cvtpk(v0.z, v0.w);
    r.u.z = cvtpk(v1.x, v1.y); r.u.w = cvtpk(v1.z, v1.w);
    return r.b;
}
__device__ __forceinline__ float b2f(ushort s) {
    union { uint u; float f; } v; v.u = ((uint)s) << 16; return v.f;
}
__device__ __forceinline__ void unpack4(uint2 v, float* o) {
    union { uint u; float f; } x;
    x.u = v.x << 16;          o[0] = x.f;
    x.u = v.x & 0xffff0000u;  o[1] = x.f;
    x.u = v.y << 16;          o[2] = x.f;
    x.u = v.y & 0xffff0000u;  o[3] = x.f;
}

// ---------------- fused setup: weight transposes + dst histogram ----------------
__global__ void setup_kernel(const float* __restrict__ We, const float* __restrict__ Weo,
                             const float* __restrict__ Wn, const float* __restrict__ Wn1,
                             const float* __restrict__ Wn2, const int* __restrict__ dst,
                             ushort* __restrict__ Wet, ushort* __restrict__ Weot,
                             ushort* __restrict__ Wnt, ushort* __restrict__ Wn1t,
                             ushort* __restrict__ Wn2t, int* __restrict__ cnt,
                             int n_edges) {
    int i = blockIdx.x * 256 + threadIdx.x;
    if (i < H * EF) {
        int j = i / EF, k = i % EF;
        Wet[i] = (ushort)cvtpk(We[(size_t)k * H + j], 0.f);
        int o = i / H, j2 = i % H;
        Weot[i] = (ushort)cvtpk(Weo[(size_t)j2 * EF + o], 0.f);
    }
    if (i < H * NF) {
        int o = i >> 7, k = i & 127;
        Wnt[i] = (ushort)cvtpk(Wn[(size_t)k * H + o], 0.f);
        int o2 = i >> 9, k2 = i & 511;
        Wn2t[i] = (ushort)cvtpk(Wn2[(size_t)k2 * NF + o2], 0.f);
    }
    if (i < H * H) {
        int o = i >> 9, k = i & 511;
        Wn1t[i] = (ushort)cvtpk(Wn1[(size_t)k * H + o], 0.f);
    }
    // histogram (grid-stride over edges)
    const int nthreads = gridDim.x * 256;
    for (int e = i; e < n_edges; e += nthreads)
        atomicAdd(&cnt[dst[e]], 1);
}

__global__ void scan_kernel(int* __restrict__ cnt, int n_nodes) {
    __shared__ int part[1024];
    const int t = threadIdx.x;
    const int per = (n_nodes + 1023) / 1024;
    int s = 0;
    for (int i = 0; i < per; ++i) {
        int idx = t * per + i;
        if (idx < n_nodes) s += cnt[idx];
    }
    part[t] = s;
    __syncthreads();
    for (int off = 1; off < 1024; off <<= 1) {
        int v = (t >= off) ? part[t - off] : 0;
        __syncthreads();
        part[t] += v;
        __syncthreads();
    }
    int acc = part[t] - s;
    for (int i = 0; i < per; ++i) {
        int idx = t * per + i;
        if (idx < n_nodes) {
            int c = cnt[idx];
            cnt[idx] = acc;
            acc += c;
        }
    }
}

// Kernel 1 (fused): blocks [0, nNE) do node_expand (MFMA, swapped operands);
// blocks [nNE, nNE+nSC) do the sort scatter.
// hc layout: per node, 128 groups of 16B: [h pair | h pair | c pair | c pair]
__global__ __launch_bounds__(256) void node_expand_kernel(
        const float* __restrict__ hfeats, const float* __restrict__ cfeats,
        const ushort* __restrict__ Wnt, const float* __restrict__ bn,
        const float* __restrict__ Wc, const float* __restrict__ bc,
        ushort* __restrict__ hc, int n_nodes,
        const int* __restrict__ dst, int* __restrict__ cursor,
        int* __restrict__ perm, int n_edges, int nNE) {
    const int t = threadIdx.x;
    if (blockIdx.x >= nNE) {
        // ---- scatter part ----
        int i = (blockIdx.x - nNE) * 256 + t;
        if (i < n_edges) {
            int pos = atomicAdd(&cursor[dst[i]], 1);
            perm[pos] = i;
        }
        return;
    }
    __shared__ ushort hf[32 * NF];
    __shared__ float cf[32][4];
    const int lane = t & 63;
    const int w = t >> 6;
    const int node0 = blockIdx.x * 32;

    for (int i = t; i < 32 * 16; i += 256) {
        int row = i >> 4, g = i & 15;
        int node = node0 + row; if (node >= n_nodes) node = n_nodes - 1;
        const float* p = hfeats + (size_t)node * NF + g * 8;
        float4 v0 = *(const float4*)p;
        float4 v1 = *(const float4*)(p + 4);
        ((bf16x8*)hf)[row * 16 + (g ^ (row & 7))] = pack8(v0, v1);
    }
    for (int i = t; i < 32 * CF; i += 256) {
        int n = i / CF, k = i % CF;
        int node = node0 + n; if (node >= n_nodes) node = n_nodes - 1;
        cf[n][k] = cfeats[(size_t)node * CF + k];
    }
    __syncthreads();

    const int ar = lane & 15;
    const int hi = lane >> 4;
    const int ak = hi * 8;

    f32x4 acc[2][8];
    #pragma unroll
    for (int nt = 0; nt < 2; ++nt)
        #pragma unroll
        for (int q = 0; q < 8; ++q) { f32x4 z = {0.f,0.f,0.f,0.f}; acc[nt][q] = z; }

    for (int kstep = 0; kstep < NF / 32; ++kstep) {
        bf16x8 nfrag[2];
        #pragma unroll
        for (int nt = 0; nt < 2; ++nt) {
            int r = nt * 16 + ar;
            int g = kstep * 4 + hi;
            nfrag[nt] = ((const bf16x8*)hf)[r * 16 + (g ^ (r & 7))];
        }
        #pragma unroll
        for (int q = 0; q < 8; ++q) {
            bf16x8 wf = *(const bf16x8*)(Wnt + (size_t)((w * 8 + q) * 16 + ar) * NF + kstep * 32 + ak);
            acc[0][q] = __builtin_amdgcn_mfma_f32_16x16x32_bf16(wf, nfrag[0], acc[0][q], 0, 0, 0);
            acc[1][q] = __builtin_amdgcn_mfma_f32_16x16x32_bf16(wf, nfrag[1], acc[1][q], 0, 0, 0);
        }
    }
    #pragma unroll
    for (int q = 0; q < 8; ++q) {
        const int jbase = (w * 8 + q) * 16 + hi * 4;
        const float4 bv = *(const float4*)(bn + jbase);
        #pragma unroll
        for (int nt = 0; nt < 2; ++nt) {
            int node = node0 + nt * 16 + ar;
            if (node < n_nodes) {
                uint2 pk;
                pk.x = cvtpk(celu_f(acc[nt][q][0] + bv.x), celu_f(acc[nt][q][1] + bv.y));
                pk.y = cvtpk(celu_f(acc[nt][q][2] + bv.z), celu_f(acc[nt][q][3] + bv.w));
                *(uint2*)(hc + (size_t)node * 1024 + (jbase >> 2) * 8) = pk;
            }
        }
    }

    // coord expansion
    for (int i = t; i < 32 * 64; i += 256) {
        int n = i >> 6, gj = i & 63;
        int node = node0 + n;
        if (node < n_nodes) {
            int j = gj * 8;
            float c0 = cf[n][0], c1 = cf[n][1], c2 = cf[n][2];
            float v[8];
            #pragma unroll
            for (int u = 0; u < 8; ++u)
                v[u] = celu_f(bc[j + u] + c0 * Wc[j + u] + c1 * Wc[H + j + u] + c2 * Wc[2 * H + j + u]);
            uint2 p0, p1;
            p0.x = cvtpk(v[0], v[1]); p0.y = cvtpk(v[2], v[3]);
            p1.x = cvtpk(v[4], v[5]); p1.y = cvtpk(v[6], v[7]);
            *(uint2*)(hc + (size_t)node * 1024 + (2 * gj) * 8 + 4) = p0;
            *(uint2*)(hc + (size_t)node * 1024 + (2 * gj + 1) * 8 + 4) = p1;
        }
    }
}

// Kernel 2 (fused): blocks [0, nEB) = edge work (512 threads, 8 waves);
// blocks [nEB, ...) = c_out (8 nodes per block, one per wave).
__global__ __launch_bounds__(512, 4) void edge_kernel(
        const float* __restrict__ efeats,
        const int* __restrict__ src, const int* __restrict__ dst,
        const int* __restrict__ perm,
        const ushort* __restrict__ Wet, const float* __restrict__ be,
        const ushort* __restrict__ Weot, const float* __restrict__ beo,
        const ushort* __restrict__ hc,
        float* __restrict__ k_acc, float* __restrict__ e_out, int n_edges,
        int nEB,
        const float* __restrict__ cfeats, const float* __restrict__ Wco,
        const float* __restrict__ bco, float* __restrict__ c_out, int n_nodes) {
    const int t = threadIdx.x;
    const int lane = t & 63;
    const int w = t >> 6;              // 0..7

    if (blockIdx.x >= nEB) {
        // ---- c_out part: 8 nodes/block, one per wave ----
        const int node = (blockIdx.x - nEB) * 8 + w;
        if (node >= n_nodes) return;
        uint2 cv0 = *(const uint2*)(hc + (size_t)node * 1024 + (2 * lane) * 8 + 4);
        uint2 cv1 = *(const uint2*)(hc + (size_t)node * 1024 + (2 * lane + 1) * 8 + 4);
        float cv[8];
        unpack4(cv0, cv);
        unpack4(cv1, cv + 4);
        float a0 = 0.f, a1 = 0.f, a2 = 0.f;
        #pragma unroll
        for (int u = 0; u < 8; ++u) {
            int j = lane * 8 + u;
            a0 += cv[u] * Wco[j * CF + 0];
            a1 += cv[u] * Wco[j * CF + 1];
            a2 += cv[u] * Wco[j * CF + 2];
        }
        #pragma unroll
        for (int m = 32; m >= 1; m >>= 1) {
            a0 += __shfl_xor(a0, m);
            a1 += __shfl_xor(a1, m);
            a2 += __shfl_xor(a2, m);
        }
        if (lane < 3) {
            float s = (lane == 0) ? a0 : (lane == 1) ? a1 : a2;
            c_out[(size_t)node * CF + lane] = cfeats[(size_t)node * CF + lane] + celu_f(bco[lane] + s);
        }
        return;
    }

    __shared__ ushort e512[EB * 512];        // 32 KB
    __shared__ int s_perm[EB], s_src[EB], s_dst[EB];

    const int q = nEB >> 3, r = nEB & 7;
    const int xcd = blockIdx.x & 7, sub = blockIdx.x >> 3;
    const int bid = (xcd < r ? xcd * (q + 1) : r * (q + 1) + (xcd - r) * q) + sub;
    const int e0 = bid * EB;

    if (t < EB) {
        int e = e0 + t;
        int pe = (e < n_edges) ? perm[e] : -1;
        s_perm[t] = pe;
        s_src[t] = (pe >= 0) ? src[pe] : 0;
        s_dst[t] = (pe >= 0) ? dst[pe] : -1;
    }
    __syncthreads();

    const int ar = lane & 15;
    const int hi = lane >> 4;
    const int ak = hi * 8;

    // B-wave early prefetch state (chunk 0 global gathers issued before phase A)
    const int grp = t >> 7;            // 0: edges 0-15, 1: edges 16-31 (valid for w<4)
    const int ct = t & 127;
    const int j0 = ct * 4;
    const int g = j0 >> 3, go = j0 & 7;
    const int ebase = grp * 16;
    uint4 svb[2][4];
    uint2 cdb[2][4];
    uint2 evb[2][4];
    if (w < 4) {
        #pragma unroll
        for (int j = 0; j < 4; ++j) {
            const int e = ebase + j;
            const int s_ = s_src[e];
            int dc = s_dst[e]; dc = (dc < 0) ? 0 : dc;
            svb[0][j] = *(const uint4*)(hc + (size_t)s_ * 1024 + ct * 8);
            cdb[0][j] = *(const uint2*)(hc + (size_t)dc * 1024 + ct * 8 + 4);
        }
    }

    // ---- Phase A (8 waves, 4 q-tiles each): e512 = celu(ef @ We + be) ----
    {
        bf16x8 wfrag[4];
        #pragma unroll
        for (int qq = 0; qq < 4; ++qq)
            wfrag[qq] = *(const bf16x8*)(Wet + (size_t)((w * 4 + qq) * 16 + ar) * EF + ak);
        #pragma unroll
        for (int et = 0; et < 2; ++et) {
            bf16x8 efrag;
            {
                int pe = s_perm[et * 16 + ar];
                if (pe < 0) pe = 0;
                const float* p = efeats + (size_t)pe * EF + ak;
                float4 v0 = *(const float4*)p;
                float4 v1 = *(const float4*)(p + 4);
                efrag = pack8(v0, v1);
            }
            f32x4 acc[4];
            #pragma unroll
            for (int qq = 0; qq < 4; ++qq) { f32x4 z = {0.f,0.f,0.f,0.f}; acc[qq] = z; }
            #pragma unroll
            for (int qq = 0; qq < 4; ++qq)
                acc[qq] = __builtin_amdgcn_mfma_f32_16x16x32_bf16(wfrag[qq], efrag, acc[qq], 0, 0, 0);
            const int e_l = et * 16 + ar;
            #pragma unroll
            for (int qq = 0; qq < 4; ++qq) {
                const int jbase = (w * 4 + qq) * 16 + hi * 4;
                const float4 bv = *(const float4*)(be + jbase);
                uint2 pk;
                pk.x = cvtpk(celu_f(acc[qq][0] + bv.x), celu_f(acc[qq][1] + bv.y));
                pk.y = cvtpk(celu_f(acc[qq][2] + bv.z), celu_f(acc[qq][3] + bv.w));
                const int gs = (jbase >> 3) ^ (e_l & 7);
                *(uint2*)(&e512[e_l * 512 + gs * 8 + (jbase & 7)]) = pk;
            }
        }
    }
    __syncthreads();

    if (w < 4) {
        // ---- Phase B (waves 0-3): software-pipelined chunks of 4 ----
        float a_[4];
        a_[0] = a_[1] = a_[2] = a_[3] = 0.f;
        int cur = -1;

        // finish chunk 0 prefetch (LDS part, needs phase-A sync)
        #pragma unroll
        for (int j = 0; j < 4; ++j) {
            const int e = ebase + j;
            evb[0][j] = *(const uint2*)(&e512[e * 512 + (g ^ (e & 7)) * 8 + go]);
        }

        #pragma unroll
        for (int c = 0; c < 4; ++c) {
            const int cb = c & 1, nb = cb ^ 1;
            if (c < 3) {
                #pragma unroll
                for (int j = 0; j < 4; ++j) {
                    const int e = ebase + (c + 1) * 4 + j;
                    const int s_ = s_src[e];
                    int dc = s_dst[e]; dc = (dc < 0) ? 0 : dc;
                    svb[nb][j] = *(const uint4*)(hc + (size_t)s_ * 1024 + ct * 8);
                    cdb[nb][j] = *(const uint2*)(hc + (size_t)dc * 1024 + ct * 8 + 4);
                    evb[nb][j] = *(const uint2*)(&e512[e * 512 + (g ^ (e & 7)) * 8 + go]);
                }
            }
            #pragma unroll
            for (int j = 0; j < 4; ++j) {
                const int e = ebase + c * 4 + j;
                const int d = __builtin_amdgcn_readfirstlane(s_dst[e]);
                if (d != cur) {
                    if (cur >= 0) {
                        #pragma unroll
                        for (int u = 0; u < 4; ++u)
                            atomicAdd(&k_acc[(size_t)cur * H + j0 + u], a_[u]);
                        a_[0] = a_[1] = a_[2] = a_[3] = 0.f;
                    }
                    cur = d;
                }
                if (d >= 0) {
                    float hs_[4], cs_[4], cd_[4], ev_[4];
                    uint2 hv; hv.x = svb[cb][j].x; hv.y = svb[cb][j].y;
                    uint2 cv; cv.x = svb[cb][j].z; cv.y = svb[cb][j].w;
                    unpack4(hv, hs_);
                    unpack4(cv, cs_);
                    unpack4(cdb[cb][j], cd_);
                    unpack4(evb[cb][j], ev_);
                    #pragma unroll
                    for (int u = 0; u < 4; ++u)
                        a_[u] += fabsf(cd_[u] - cs_[u]) * (hs_[u] * ev_[u]);
                }
            }
        }
        if (cur >= 0) {
            #pragma unroll
            for (int u = 0; u < 4; ++u)
                atomicAdd(&k_acc[(size_t)cur * H + j0 + u], a_[u]);
        }
    } else {
        // ---- Phase C (waves 4-7): e_out = efeats + celu(e512 @ Weo + beo) ----
        const int wc = w - 4;
        const int ot = wc & 1, et = wc >> 1;
        const int e_l = et * 16 + ar;
        f32x4 accc = {0.f, 0.f, 0.f, 0.f};
        #pragma unroll
        for (int kt = 0; kt < 16; ++kt) {
            bf16x8 wfC = *(const bf16x8*)(Weot + (size_t)(ot * 16 + ar) * H + kt * 32 + ak);
            const int gs = (kt * 4 + hi) ^ (e_l & 7);
            bf16x8 b = *(const bf16x8*)(&e512[e_l * 512 + gs * 8]);
            accc = __builtin_amdgcn_mfma_f32_16x16x32_bf16(wfC, b, accc, 0, 0, 0);
        }
        const int pe = s_perm[e_l];
        if (pe >= 0) {
            const int obase = ot * 16 + hi * 4;
            const float4 bo = *(const float4*)(beo + obase);
            size_t idx = (size_t)pe * EF + obase;
            float4 ef4 = *(const float4*)(efeats + idx);
            float4 o;
            o.x = ef4.x + celu_f(accc[0] + bo.x);
            o.y = ef4.y + celu_f(accc[1] + bo.y);
            o.z = ef4.z + celu_f(accc[2] + bo.z);
            o.w = ef4.w + celu_f(accc[3] + bo.w);
            *(float4*)(e_out + idx) = o;
        }
    }
}

// Kernel 3 (MFMA swapped): h_out = hfeats + celu(celu(k@Wn1+bn1)@Wn2+bn2)
__global__ __launch_bounds__(256) void node_out_kernel(
        const float* __restrict__ hfeats, const float* __restrict__ k_acc,
        const ushort* __restrict__ Wn1t, const float* __restrict__ bn1,
        const ushort* __restrict__ Wn2t, const float* __restrict__ bn2,
        float* __restrict__ h_out, int n_nodes) {
    __shared__ ushort kt_s[32 * H];
    const int t = threadIdx.x;
    const int lane = t & 63;
    const int w = t >> 6;
    const int node0 = blockIdx.x * 32;

    for (int i = t; i < 32 * 64; i += 256) {
        int row = i >> 6, g = i & 63;
        int node = node0 + row; if (node >= n_nodes) node = n_nodes - 1;
        const float* p = k_acc + (size_t)node * H + g * 8;
        float4 v0 = *(const float4*)p;
        float4 v1 = *(const float4*)(p + 4);
        ((bf16x8*)kt_s)[row * 64 + (g ^ (row & 7))] = pack8(v0, v1);
    }
    __syncthreads();

    const int ar = lane & 15;
    const int hi = lane >> 4;
    const int ak = hi * 8;

    f32x4 acc[2][8];
    #pragma unroll
    for (int nt = 0; nt < 2; ++nt)
        #pragma unroll
        for (int q = 0; q < 8; ++q) { f32x4 z = {0.f,0.f,0.f,0.f}; acc[nt][q] = z; }

    for (int kstep = 0; kstep < H / 32; ++kstep) {
        bf16x8 kfrag[2];
        #pragma unroll
        for (int nt = 0; nt < 2; ++nt) {
            int rr = nt * 16 + ar;
            int g = kstep * 4 + hi;
            kfrag[nt] = ((const bf16x8*)kt_s)[rr * 64 + (g ^ (rr & 7))];
        }
        #pragma unroll
        for (int q = 0; q < 8; ++q) {
            bf16x8 wf = *(const bf16x8*)(Wn1t + (size_t)((w * 8 + q) * 16 + ar) * H + kstep * 32 + ak);
            acc[0][q] = __builtin_amdgcn_mfma_f32_16x16x32_bf16(wf, kfrag[0], acc[0][q], 0, 0, 0);
            acc[1][q] = __builtin_amdgcn_mfma_f32_16x16x32_bf16(wf, kfrag[1], acc[1][q], 0, 0, 0);
        }
    }
    __syncthreads();

    #pragma unroll
    for (int q = 0; q < 8; ++q) {
        const int jbase = (w * 8 + q) * 16 + hi * 4;
        const float4 bv = *(const float4*)(bn1 + jbase);
        #pragma unroll
        for (int nt = 0; nt < 2; ++nt) {
            const int rr = nt * 16 + ar;
            uint2 pk;
            pk.x = cvtpk(celu_f(acc[nt][q][0] + bv.x), celu_f(acc[nt][q][1] + bv.y));
            pk.y = cvtpk(celu_f(acc[nt][q][2] + bv.z), celu_f(acc[nt][q][3] + bv.w));
            const int gs = (jbase >> 3) ^ (rr & 7);
            *(uint2*)(&kt_s[rr * 512 + gs * 8 + (jbase & 7)]) = pk;
        }
    }
    __syncthreads();

    f32x4 acc2[2][2];
    #pragma unroll
    for (int nt = 0; nt < 2; ++nt)
        #pragma unroll
        for (int ct = 0; ct < 2; ++ct) { f32x4 z = {0.f,0.f,0.f,0.f}; acc2[nt][ct] = z; }

    for (int kstep = 0; kstep < H / 32; ++kstep) {
        bf16x8 tfrag[2];
        #pragma unroll
        for (int nt = 0; nt < 2; ++nt) {
            int rr = nt * 16 + ar;
            int g = kstep * 4 + hi;
            tfrag[nt] = ((const bf16x8*)kt_s)[rr * 64 + (g ^ (rr & 7))];
        }
        #pragma unroll
        for (int ct = 0; ct < 2; ++ct) {
            bf16x8 wf = *(const bf16x8*)(Wn2t + (size_t)((w * 2 + ct) * 16 + ar) * H + kstep * 32 + ak);
            acc2[0][ct] = __builtin_amdgcn_mfma_f32_16x16x32_bf16(wf, tfrag[0], acc2[0][ct], 0, 0, 0);
            acc2[1][ct] = __builtin_amdgcn_mfma_f32_16x16x32_bf16(wf, tfrag[1], acc2[1][ct], 0, 0, 0);
        }
    }
    #pragma unroll
    for (int ct = 0; ct < 2; ++ct) {
        const int jbase = (w * 2 + ct) * 16 + hi * 4;
        const float4 bv = *(const float4*)(bn2 + jbase);
        #pragma unroll
        for (int nt = 0; nt < 2; ++nt) {
            const int node = node0 + nt * 16 + ar;
            if (node < n_nodes) {
                size_t idx = (size_t)node * NF + jbase;
                float4 hf4 = *(const float4*)(hfeats + idx);
                float4 o;
                o.x = hf4.x + celu_f(acc2[nt][ct][0] + bv.x);
                o.y = hf4.y + celu_f(acc2[nt][ct][1] + bv.y);
                o.z = hf4.z + celu_f(acc2[nt][ct][2] + bv.z);
                o.w = hf4.w + celu_f(acc2[nt][ct][3] + bv.w);
                *(float4*)(h_out + idx) = o;
            }
        }
    }
}

extern "C" void kernel_launch(void* const* d_in, const int* in_sizes, int n_in,
                              void* d_out, int out_size, void* d_ws, size_t ws_size,
                              hipStream_t stream) {
    const float* hfeats = (const float*)d_in[0];
    const float* cfeats = (const float*)d_in[1];
    const float* efeats = (const float*)d_in[2];
    const int*   src    = (const int*)d_in[3];
    const int*   dst    = (const int*)d_in[4];
    const float* Wn  = (const float*)d_in[5];  const float* bn  = (const float*)d_in[6];
    const float* We  = (const float*)d_in[7];  const float* be  = (const float*)d_in[8];
    const float* Wc  = (const float*)d_in[9];  const float* bc  = (const float*)d_in[10];
    const float* Wn1 = (const float*)d_in[11]; const float* bn1 = (const float*)d_in[12];
    const float* Wn2 = (const float*)d_in[13]; const float* bn2 = (const float*)d_in[14];
    const float* Weo = (const float*)d_in[15]; const float* beo = (const float*)d_in[16];
    const float* Wco = (const float*)d_in[17]; const float* bco = (const float*)d_in[18];

    const int n_nodes = in_sizes[0] / NF;
    const int n_edges = in_sizes[2] / EF;

    float*  k_buf = (float*)d_ws;                                   // [N,H] f32
    ushort* hc    = (ushort*)(k_buf + (size_t)n_nodes * H);         // [N,2H] bf16 interleaved
    ushort* Wet   = hc + (size_t)n_nodes * H * 2;                   // [H,EF]
    ushort* Weot  = Wet + (size_t)H * EF;                           // [EF,H]
    ushort* Wnt   = Weot + (size_t)H * EF;                          // [H,NF]
    ushort* Wn1t  = Wnt + (size_t)H * NF;                           // [H,H]
    ushort* Wn2t  = Wn1t + (size_t)H * H;                           // [NF,H]
    int*    cnt   = (int*)(Wn2t + (size_t)NF * H);                  // [N]
    int*    perm  = cnt + n_nodes;                                  // [E]

    float* h_out = (float*)d_out;
    float* c_out = h_out + (size_t)n_nodes * NF;
    float* e_out = c_out + (size_t)n_nodes * CF;

    hipMemsetAsync(k_buf, 0, (size_t)n_nodes * H * sizeof(float), stream);
    hipMemsetAsync(cnt, 0, (size_t)n_nodes * sizeof(int), stream);

    setup_kernel<<<(H * H + 255) / 256, 256, 0, stream>>>(
        We, Weo, Wn, Wn1, Wn2, dst, Wet, Weot, Wnt, Wn1t, Wn2t, cnt, n_edges);

    scan_kernel<<<1, 1024, 0, stream>>>(cnt, n_nodes);

    const int nNE = (n_nodes + 31) / 32;
    const int nSC = (n_edges + 255) / 256;
    node_expand_kernel<<<nNE + nSC, 256, 0, stream>>>(
        hfeats, cfeats, Wnt, bn, Wc, bc, hc, n_nodes,
        dst, cnt, perm, n_edges, nNE);

    const int nEB = (n_edges + EB - 1) / EB;
    const int nCO = (n_nodes + 7) / 8;
    edge_kernel<<<nEB + nCO, 512, 0, stream>>>(
        efeats, src, dst, perm, Wet, be, Weot, beo, hc, k_buf, e_out, n_edges,
        nEB, cfeats, Wco, bco, c_out, n_nodes);

    node_out_kernel<<<(n_nodes + 31) / 32, 256, 0, stream>>>(
        hfeats, k_buf, Wn1t, bn1, Wn2t, bn2, h_out, n_nodes);
}

// Round 14
// 420.064 us; speedup vs baseline: 1.1895x; 1.0466x over previous
//
#include <hip/hip_runtime.h>
#include <hip/hip_bf16.h>

#define NF 128
#define EF 32
#define CF 3
#define H  512
#define EB 32   // edges per block (edge_kernel tile)

typedef __attribute__((ext_vector_type(8))) short bf16x8;
typedef __attribute__((ext_vector_type(4))) float f32x4;

// branch-free CELU: max(x, exp(min(x,0))-1)
__device__ __forceinline__ float celu_f(float x) {
    return fmaxf(x, __expf(fminf(x, 0.0f)) - 1.0f);
}
// HW packed f32->bf16 (RNE), 1 instruction for 2 values
__device__ __forceinline__ uint cvtpk(float lo, float hi) {
    uint r;
    asm("v_cvt_pk_bf16_f32 %0, %1, %2" : "=v"(r) : "v"(lo), "v"(hi));
    return r;
}
__device__ __forceinline__ bf16x8 pack8(float4 v0, float4 v1) {
    union { uint4 u; bf16x8 b; } r;
    r.u.x = cvtpk(v0.x, v0.y); r.u.y = cvtpk(v0.z, v0.w);
    r.u.z = cvtpk(v1.x, v1.y); r.u.w = cvtpk(v1.z, v1.w);
    return r.b;
}
__device__ __forceinline__ float b2f(ushort s) {
    union { uint u; float f; } v; v.u = ((uint)s) << 16; return v.f;
}
__device__ __forceinline__ void unpack4(uint2 v, float* o) {
    union { uint u; float f; } x;
    x.u = v.x << 16;          o[0] = x.f;
    x.u = v.x & 0xffff0000u;  o[1] = x.f;
    x.u = v.y << 16;          o[2] = x.f;
    x.u = v.y & 0xffff0000u;  o[3] = x.f;
}

// ---------------- fused setup: weight transposes + dst histogram + k_buf zero ----------------
__global__ void setup_kernel(const float* __restrict__ We, const float* __restrict__ Weo,
                             const float* __restrict__ Wn, const float* __restrict__ Wn1,
                             const float* __restrict__ Wn2, const int* __restrict__ dst,
                             ushort* __restrict__ Wet, ushort* __restrict__ Weot,
                             ushort* __restrict__ Wnt, ushort* __restrict__ Wn1t,
                             ushort* __restrict__ Wn2t, int* __restrict__ cnt,
                             float* __restrict__ k_buf, int n_edges, int nk4) {
    int i = blockIdx.x * 256 + threadIdx.x;
    if (i < H * EF) {
        int j = i / EF, k = i % EF;
        Wet[i] = (ushort)cvtpk(We[(size_t)k * H + j], 0.f);
        int o = i / H, j2 = i % H;
        Weot[i] = (ushort)cvtpk(Weo[(size_t)j2 * EF + o], 0.f);
    }
    if (i < H * NF) {
        int o = i >> 7, k = i & 127;
        Wnt[i] = (ushort)cvtpk(Wn[(size_t)k * H + o], 0.f);
        int o2 = i >> 9, k2 = i & 511;
        Wn2t[i] = (ushort)cvtpk(Wn2[(size_t)k2 * NF + o2], 0.f);
    }
    if (i < H * H) {
        int o = i >> 9, k = i & 511;
        Wn1t[i] = (ushort)cvtpk(Wn1[(size_t)k * H + o], 0.f);
    }
    const int nthreads = gridDim.x * 256;
    // zero k_buf (float4 grid-stride)
    float4 z4 = {0.f, 0.f, 0.f, 0.f};
    for (int p = i; p < nk4; p += nthreads)
        ((float4*)k_buf)[p] = z4;
    // histogram (grid-stride over edges)
    for (int e = i; e < n_edges; e += nthreads)
        atomicAdd(&cnt[dst[e]], 1);
}

__global__ void scan_kernel(int* __restrict__ cnt, int n_nodes) {
    __shared__ int part[1024];
    const int t = threadIdx.x;
    const int per = (n_nodes + 1023) / 1024;
    int s = 0;
    for (int i = 0; i < per; ++i) {
        int idx = t * per + i;
        if (idx < n_nodes) s += cnt[idx];
    }
    part[t] = s;
    __syncthreads();
    for (int off = 1; off < 1024; off <<= 1) {
        int v = (t >= off) ? part[t - off] : 0;
        __syncthreads();
        part[t] += v;
        __syncthreads();
    }
    int acc = part[t] - s;
    for (int i = 0; i < per; ++i) {
        int idx = t * per + i;
        if (idx < n_nodes) {
            int c = cnt[idx];
            cnt[idx] = acc;
            acc += c;
        }
    }
}

// Kernel 1 (fused): blocks [0, nNE) node_expand (MFMA, swapped); blocks [nNE,...) scatter.
// hc layout: per node, 128 groups of 16B: [h pair | h pair | c pair | c pair]
__global__ __launch_bounds__(256) void node_expand_kernel(
        const float* __restrict__ hfeats, const float* __restrict__ cfeats,
        const ushort* __restrict__ Wnt, const float* __restrict__ bn,
        const float* __restrict__ Wc, const float* __restrict__ bc,
        ushort* __restrict__ hc, int n_nodes,
        const int* __restrict__ dst, int* __restrict__ cursor,
        int* __restrict__ perm, int n_edges, int nNE) {
    const int t = threadIdx.x;
    if (blockIdx.x >= nNE) {
        int i = (blockIdx.x - nNE) * 256 + t;
        if (i < n_edges) {
            int pos = atomicAdd(&cursor[dst[i]], 1);
            perm[pos] = i;
        }
        return;
    }
    __shared__ ushort hf[32 * NF];
    __shared__ float cf[32][4];
    const int lane = t & 63;
    const int w = t >> 6;
    const int node0 = blockIdx.x * 32;

    for (int i = t; i < 32 * 16; i += 256) {
        int row = i >> 4, g = i & 15;
        int node = node0 + row; if (node >= n_nodes) node = n_nodes - 1;
        const float* p = hfeats + (size_t)node * NF + g * 8;
        float4 v0 = *(const float4*)p;
        float4 v1 = *(const float4*)(p + 4);
        ((bf16x8*)hf)[row * 16 + (g ^ (row & 7))] = pack8(v0, v1);
    }
    for (int i = t; i < 32 * CF; i += 256) {
        int n = i / CF, k = i % CF;
        int node = node0 + n; if (node >= n_nodes) node = n_nodes - 1;
        cf[n][k] = cfeats[(size_t)node * CF + k];
    }
    __syncthreads();

    const int ar = lane & 15;
    const int hi = lane >> 4;
    const int ak = hi * 8;

    f32x4 acc[2][8];
    #pragma unroll
    for (int nt = 0; nt < 2; ++nt)
        #pragma unroll
        for (int q = 0; q < 8; ++q) { f32x4 z = {0.f,0.f,0.f,0.f}; acc[nt][q] = z; }

    for (int kstep = 0; kstep < NF / 32; ++kstep) {
        bf16x8 nfrag[2];
        #pragma unroll
        for (int nt = 0; nt < 2; ++nt) {
            int r = nt * 16 + ar;
            int g = kstep * 4 + hi;
            nfrag[nt] = ((const bf16x8*)hf)[r * 16 + (g ^ (r & 7))];
        }
        #pragma unroll
        for (int q = 0; q < 8; ++q) {
            bf16x8 wf = *(const bf16x8*)(Wnt + (size_t)((w * 8 + q) * 16 + ar) * NF + kstep * 32 + ak);
            acc[0][q] = __builtin_amdgcn_mfma_f32_16x16x32_bf16(wf, nfrag[0], acc[0][q], 0, 0, 0);
            acc[1][q] = __builtin_amdgcn_mfma_f32_16x16x32_bf16(wf, nfrag[1], acc[1][q], 0, 0, 0);
        }
    }
    #pragma unroll
    for (int q = 0; q < 8; ++q) {
        const int jbase = (w * 8 + q) * 16 + hi * 4;
        const float4 bv = *(const float4*)(bn + jbase);
        #pragma unroll
        for (int nt = 0; nt < 2; ++nt) {
            int node = node0 + nt * 16 + ar;
            if (node < n_nodes) {
                uint2 pk;
                pk.x = cvtpk(celu_f(acc[nt][q][0] + bv.x), celu_f(acc[nt][q][1] + bv.y));
                pk.y = cvtpk(celu_f(acc[nt][q][2] + bv.z), celu_f(acc[nt][q][3] + bv.w));
                *(uint2*)(hc + (size_t)node * 1024 + (jbase >> 2) * 8) = pk;
            }
        }
    }

    // coord expansion
    for (int i = t; i < 32 * 64; i += 256) {
        int n = i >> 6, gj = i & 63;
        int node = node0 + n;
        if (node < n_nodes) {
            int j = gj * 8;
            float c0 = cf[n][0], c1 = cf[n][1], c2 = cf[n][2];
            float v[8];
            #pragma unroll
            for (int u = 0; u < 8; ++u)
                v[u] = celu_f(bc[j + u] + c0 * Wc[j + u] + c1 * Wc[H + j + u] + c2 * Wc[2 * H + j + u]);
            uint2 p0, p1;
            p0.x = cvtpk(v[0], v[1]); p0.y = cvtpk(v[2], v[3]);
            p1.x = cvtpk(v[4], v[5]); p1.y = cvtpk(v[6], v[7]);
            *(uint2*)(hc + (size_t)node * 1024 + (2 * gj) * 8 + 4) = p0;
            *(uint2*)(hc + (size_t)node * 1024 + (2 * gj + 1) * 8 + 4) = p1;
        }
    }
}

// Kernel 2 (fused): blocks [0, nEB) = edge work; blocks [nEB,...) = c_out.
__global__ __launch_bounds__(512, 4) void edge_kernel(
        const float* __restrict__ efeats,
        const int* __restrict__ src, const int* __restrict__ dst,
        const int* __restrict__ perm,
        const ushort* __restrict__ Wet, const float* __restrict__ be,
        const ushort* __restrict__ Weot, const float* __restrict__ beo,
        const ushort* __restrict__ hc,
        float* __restrict__ k_acc, float* __restrict__ e_out, int n_edges,
        int nEB,
        const float* __restrict__ cfeats, const float* __restrict__ Wco,
        const float* __restrict__ bco, float* __restrict__ c_out, int n_nodes) {
    const int t = threadIdx.x;
    const int lane = t & 63;
    const int w = t >> 6;              // 0..7

    if (blockIdx.x >= nEB) {
        const int node = (blockIdx.x - nEB) * 8 + w;
        if (node >= n_nodes) return;
        uint2 cv0 = *(const uint2*)(hc + (size_t)node * 1024 + (2 * lane) * 8 + 4);
        uint2 cv1 = *(const uint2*)(hc + (size_t)node * 1024 + (2 * lane + 1) * 8 + 4);
        float cv[8];
        unpack4(cv0, cv);
        unpack4(cv1, cv + 4);
        float a0 = 0.f, a1 = 0.f, a2 = 0.f;
        #pragma unroll
        for (int u = 0; u < 8; ++u) {
            int j = lane * 8 + u;
            a0 += cv[u] * Wco[j * CF + 0];
            a1 += cv[u] * Wco[j * CF + 1];
            a2 += cv[u] * Wco[j * CF + 2];
        }
        #pragma unroll
        for (int m = 32; m >= 1; m >>= 1) {
            a0 += __shfl_xor(a0, m);
            a1 += __shfl_xor(a1, m);
            a2 += __shfl_xor(a2, m);
        }
        if (lane < 3) {
            float s = (lane == 0) ? a0 : (lane == 1) ? a1 : a2;
            c_out[(size_t)node * CF + lane] = cfeats[(size_t)node * CF + lane] + celu_f(bco[lane] + s);
        }
        return;
    }

    __shared__ ushort e512[EB * 512];        // 32 KB
    __shared__ int s_perm[EB], s_src[EB], s_dst[EB];

    const int q = nEB >> 3, r = nEB & 7;
    const int xcd = blockIdx.x & 7, sub = blockIdx.x >> 3;
    const int bid = (xcd < r ? xcd * (q + 1) : r * (q + 1) + (xcd - r) * q) + sub;
    const int e0 = bid * EB;

    if (t < EB) {
        int e = e0 + t;
        int pe = (e < n_edges) ? perm[e] : -1;
        s_perm[t] = pe;
        s_src[t] = (pe >= 0) ? src[pe] : 0;
        s_dst[t] = (pe >= 0) ? dst[pe] : -1;
    }
    __syncthreads();

    const int ar = lane & 15;
    const int hi = lane >> 4;
    const int ak = hi * 8;

    const int grp = t >> 7;
    const int ct = t & 127;
    const int j0 = ct * 4;
    const int g = j0 >> 3, go = j0 & 7;
    const int ebase = grp * 16;
    uint4 svb[2][4];
    uint2 cdb[2][4];
    uint2 evb[2][4];
    if (w < 4) {
        #pragma unroll
        for (int j = 0; j < 4; ++j) {
            const int e = ebase + j;
            const int s_ = s_src[e];
            int dc = s_dst[e]; dc = (dc < 0) ? 0 : dc;
            svb[0][j] = *(const uint4*)(hc + (size_t)s_ * 1024 + ct * 8);
            cdb[0][j] = *(const uint2*)(hc + (size_t)dc * 1024 + ct * 8 + 4);
        }
    }

    // ---- Phase A (8 waves, 4 q-tiles each): e512 = celu(ef @ We + be) ----
    {
        bf16x8 wfrag[4];
        #pragma unroll
        for (int qq = 0; qq < 4; ++qq)
            wfrag[qq] = *(const bf16x8*)(Wet + (size_t)((w * 4 + qq) * 16 + ar) * EF + ak);
        #pragma unroll
        for (int et = 0; et < 2; ++et) {
            bf16x8 efrag;
            {
                int pe = s_perm[et * 16 + ar];
                if (pe < 0) pe = 0;
                const float* p = efeats + (size_t)pe * EF + ak;
                float4 v0 = *(const float4*)p;
                float4 v1 = *(const float4*)(p + 4);
                efrag = pack8(v0, v1);
            }
            f32x4 acc[4];
            #pragma unroll
            for (int qq = 0; qq < 4; ++qq) { f32x4 z = {0.f,0.f,0.f,0.f}; acc[qq] = z; }
            #pragma unroll
            for (int qq = 0; qq < 4; ++qq)
                acc[qq] = __builtin_amdgcn_mfma_f32_16x16x32_bf16(wfrag[qq], efrag, acc[qq], 0, 0, 0);
            const int e_l = et * 16 + ar;
            #pragma unroll
            for (int qq = 0; qq < 4; ++qq) {
                const int jbase = (w * 4 + qq) * 16 + hi * 4;
                const float4 bv = *(const float4*)(be + jbase);
                uint2 pk;
                pk.x = cvtpk(celu_f(acc[qq][0] + bv.x), celu_f(acc[qq][1] + bv.y));
                pk.y = cvtpk(celu_f(acc[qq][2] + bv.z), celu_f(acc[qq][3] + bv.w));
                const int gs = (jbase >> 3) ^ (e_l & 7);
                *(uint2*)(&e512[e_l * 512 + gs * 8 + (jbase & 7)]) = pk;
            }
        }
    }
    __syncthreads();

    if (w < 4) {
        // ---- Phase B (waves 0-3): software-pipelined chunks of 4 ----
        float a_[4];
        a_[0] = a_[1] = a_[2] = a_[3] = 0.f;
        int cur = -1;

        #pragma unroll
        for (int j = 0; j < 4; ++j) {
            const int e = ebase + j;
            evb[0][j] = *(const uint2*)(&e512[e * 512 + (g ^ (e & 7)) * 8 + go]);
        }

        #pragma unroll
        for (int c = 0; c < 4; ++c) {
            const int cb = c & 1, nb = cb ^ 1;
            if (c < 3) {
                #pragma unroll
                for (int j = 0; j < 4; ++j) {
                    const int e = ebase + (c + 1) * 4 + j;
                    const int s_ = s_src[e];
                    int dc = s_dst[e]; dc = (dc < 0) ? 0 : dc;
                    svb[nb][j] = *(const uint4*)(hc + (size_t)s_ * 1024 + ct * 8);
                    cdb[nb][j] = *(const uint2*)(hc + (size_t)dc * 1024 + ct * 8 + 4);
                    evb[nb][j] = *(const uint2*)(&e512[e * 512 + (g ^ (e & 7)) * 8 + go]);
                }
            }
            #pragma unroll
            for (int j = 0; j < 4; ++j) {
                const int e = ebase + c * 4 + j;
                const int d = __builtin_amdgcn_readfirstlane(s_dst[e]);
                if (d != cur) {
                    if (cur >= 0) {
                        #pragma unroll
                        for (int u = 0; u < 4; ++u)
                            atomicAdd(&k_acc[(size_t)cur * H + j0 + u], a_[u]);
                        a_[0] = a_[1] = a_[2] = a_[3] = 0.f;
                    }
                    cur = d;
                }
                if (d >= 0) {
                    float hs_[4], cs_[4], cd_[4], ev_[4];
                    uint2 hv; hv.x = svb[cb][j].x; hv.y = svb[cb][j].y;
                    uint2 cv; cv.x = svb[cb][j].z; cv.y = svb[cb][j].w;
                    unpack4(hv, hs_);
                    unpack4(cv, cs_);
                    unpack4(cdb[cb][j], cd_);
                    unpack4(evb[cb][j], ev_);
                    #pragma unroll
                    for (int u = 0; u < 4; ++u)
                        a_[u] += fabsf(cd_[u] - cs_[u]) * (hs_[u] * ev_[u]);
                }
            }
        }
        if (cur >= 0) {
            #pragma unroll
            for (int u = 0; u < 4; ++u)
                atomicAdd(&k_acc[(size_t)cur * H + j0 + u], a_[u]);
        }
    } else {
        // ---- Phase C (waves 4-7): e_out = efeats + celu(e512 @ Weo + beo) ----
        const int wc = w - 4;
        const int ot = wc & 1, et = wc >> 1;
        const int e_l = et * 16 + ar;
        f32x4 accc = {0.f, 0.f, 0.f, 0.f};
        #pragma unroll
        for (int kt = 0; kt < 16; ++kt) {
            bf16x8 wfC = *(const bf16x8*)(Weot + (size_t)(ot * 16 + ar) * H + kt * 32 + ak);
            const int gs = (kt * 4 + hi) ^ (e_l & 7);
            bf16x8 b = *(const bf16x8*)(&e512[e_l * 512 + gs * 8]);
            accc = __builtin_amdgcn_mfma_f32_16x16x32_bf16(wfC, b, accc, 0, 0, 0);
        }
        const int pe = s_perm[e_l];
        if (pe >= 0) {
            const int obase = ot * 16 + hi * 4;
            const float4 bo = *(const float4*)(beo + obase);
            size_t idx = (size_t)pe * EF + obase;
            float4 ef4 = *(const float4*)(efeats + idx);
            float4 o;
            o.x = ef4.x + celu_f(accc[0] + bo.x);
            o.y = ef4.y + celu_f(accc[1] + bo.y);
            o.z = ef4.z + celu_f(accc[2] + bo.z);
            o.w = ef4.w + celu_f(accc[3] + bo.w);
            *(float4*)(e_out + idx) = o;
        }
    }
}

// Kernel 3 (MFMA swapped, 64-node tile, 512 threads):
// h_out = hfeats + celu(celu(k@Wn1+bn1)@Wn2+bn2)
__global__ __launch_bounds__(512, 4) void node_out_kernel(
        const float* __restrict__ hfeats, const float* __restrict__ k_acc,
        const ushort* __restrict__ Wn1t, const float* __restrict__ bn1,
        const ushort* __restrict__ Wn2t, const float* __restrict__ bn2,
        float* __restrict__ h_out, int n_nodes) {
    __shared__ ushort kt_s[64 * H];   // 64 KB
    const int t = threadIdx.x;
    const int lane = t & 63;
    const int w = t >> 6;             // 0..7
    const int node0 = blockIdx.x * 64;

    for (int i = t; i < 64 * 64; i += 512) {
        int row = i >> 6, g = i & 63;
        int node = node0 + row; if (node >= n_nodes) node = n_nodes - 1;
        const float* p = k_acc + (size_t)node * H + g * 8;
        float4 v0 = *(const float4*)p;
        float4 v1 = *(const float4*)(p + 4);
        ((bf16x8*)kt_s)[row * 64 + (g ^ (row & 7))] = pack8(v0, v1);
    }
    __syncthreads();

    const int ar = lane & 15;
    const int hi = lane >> 4;
    const int ak = hi * 8;

    // GEMM1 (swapped): t = celu(k @ Wn1 + bn1); wave w -> cols w*64..w*64+63 (4 q-tiles)
    f32x4 acc[4][4];
    #pragma unroll
    for (int nt = 0; nt < 4; ++nt)
        #pragma unroll
        for (int q = 0; q < 4; ++q) { f32x4 z = {0.f,0.f,0.f,0.f}; acc[nt][q] = z; }

    for (int kstep = 0; kstep < H / 32; ++kstep) {
        bf16x8 kfrag[4];
        #pragma unroll
        for (int nt = 0; nt < 4; ++nt) {
            int rr = nt * 16 + ar;
            int g = kstep * 4 + hi;
            kfrag[nt] = ((const bf16x8*)kt_s)[rr * 64 + (g ^ (rr & 7))];
        }
        #pragma unroll
        for (int q = 0; q < 4; ++q) {
            bf16x8 wf = *(const bf16x8*)(Wn1t + (size_t)((w * 4 + q) * 16 + ar) * H + kstep * 32 + ak);
            #pragma unroll
            for (int nt = 0; nt < 4; ++nt)
                acc[nt][q] = __builtin_amdgcn_mfma_f32_16x16x32_bf16(wf, kfrag[nt], acc[nt][q], 0, 0, 0);
        }
    }
    __syncthreads();   // everyone done reading k-tile

    #pragma unroll
    for (int q = 0; q < 4; ++q) {
        const int jbase = (w * 4 + q) * 16 + hi * 4;
        const float4 bv = *(const float4*)(bn1 + jbase);
        #pragma unroll
        for (int nt = 0; nt < 4; ++nt) {
            const int rr = nt * 16 + ar;
            uint2 pk;
            pk.x = cvtpk(celu_f(acc[nt][q][0] + bv.x), celu_f(acc[nt][q][1] + bv.y));
            pk.y = cvtpk(celu_f(acc[nt][q][2] + bv.z), celu_f(acc[nt][q][3] + bv.w));
            const int gs = (jbase >> 3) ^ (rr & 7);
            *(uint2*)(&kt_s[rr * 512 + gs * 8 + (jbase & 7)]) = pk;
        }
    }
    __syncthreads();

    // GEMM2 (swapped): wave w -> out cols w*16..w*16+15
    f32x4 acc2[4];
    #pragma unroll
    for (int nt = 0; nt < 4; ++nt) { f32x4 z = {0.f,0.f,0.f,0.f}; acc2[nt] = z; }

    for (int kstep = 0; kstep < H / 32; ++kstep) {
        bf16x8 wf = *(const bf16x8*)(Wn2t + (size_t)(w * 16 + ar) * H + kstep * 32 + ak);
        #pragma unroll
        for (int nt = 0; nt < 4; ++nt) {
            int rr = nt * 16 + ar;
            int g = kstep * 4 + hi;
            bf16x8 tfrag = ((const bf16x8*)kt_s)[rr * 64 + (g ^ (rr & 7))];
            acc2[nt] = __builtin_amdgcn_mfma_f32_16x16x32_bf16(wf, tfrag, acc2[nt], 0, 0, 0);
        }
    }
    {
        const int jbase = w * 16 + hi * 4;
        const float4 bv = *(const float4*)(bn2 + jbase);
        #pragma unroll
        for (int nt = 0; nt < 4; ++nt) {
            const int node = node0 + nt * 16 + ar;
            if (node < n_nodes) {
                size_t idx = (size_t)node * NF + jbase;
                float4 hf4 = *(const float4*)(hfeats + idx);
                float4 o;
                o.x = hf4.x + celu_f(acc2[nt][0] + bv.x);
                o.y = hf4.y + celu_f(acc2[nt][1] + bv.y);
                o.z = hf4.z + celu_f(acc2[nt][2] + bv.z);
                o.w = hf4.w + celu_f(acc2[nt][3] + bv.w);
                *(float4*)(h_out + idx) = o;
            }
        }
    }
}

extern "C" void kernel_launch(void* const* d_in, const int* in_sizes, int n_in,
                              void* d_out, int out_size, void* d_ws, size_t ws_size,
                              hipStream_t stream) {
    const float* hfeats = (const float*)d_in[0];
    const float* cfeats = (const float*)d_in[1];
    const float* efeats = (const float*)d_in[2];
    const int*   src    = (const int*)d_in[3];
    const int*   dst    = (const int*)d_in[4];
    const float* Wn  = (const float*)d_in[5];  const float* bn  = (const float*)d_in[6];
    const float* We  = (const float*)d_in[7];  const float* be  = (const float*)d_in[8];
    const float* Wc  = (const float*)d_in[9];  const float* bc  = (const float*)d_in[10];
    const float* Wn1 = (const float*)d_in[11]; const float* bn1 = (const float*)d_in[12];
    const float* Wn2 = (const float*)d_in[13]; const float* bn2 = (const float*)d_in[14];
    const float* Weo = (const float*)d_in[15]; const float* beo = (const float*)d_in[16];
    const float* Wco = (const float*)d_in[17]; const float* bco = (const float*)d_in[18];

    const int n_nodes = in_sizes[0] / NF;
    const int n_edges = in_sizes[2] / EF;

    float*  k_buf = (float*)d_ws;                                   // [N,H] f32
    ushort* hc    = (ushort*)(k_buf + (size_t)n_nodes * H);         // [N,2H] bf16 interleaved
    ushort* Wet   = hc + (size_t)n_nodes * H * 2;                   // [H,EF]
    ushort* Weot  = Wet + (size_t)H * EF;                           // [EF,H]
    ushort* Wnt   = Weot + (size_t)H * EF;                          // [H,NF]
    ushort* Wn1t  = Wnt + (size_t)H * NF;                           // [H,H]
    ushort* Wn2t  = Wn1t + (size_t)H * H;                           // [NF,H]
    int*    cnt   = (int*)(Wn2t + (size_t)NF * H);                  // [N]
    int*    perm  = cnt + n_nodes;                                  // [E]

    float* h_out = (float*)d_out;
    float* c_out = h_out + (size_t)n_nodes * NF;
    float* e_out = c_out + (size_t)n_nodes * CF;

    hipMemsetAsync(cnt, 0, (size_t)n_nodes * sizeof(int), stream);

    const int nk4 = (n_nodes * H) / 4;
    setup_kernel<<<(H * H + 255) / 256, 256, 0, stream>>>(
        We, Weo, Wn, Wn1, Wn2, dst, Wet, Weot, Wnt, Wn1t, Wn2t, cnt, k_buf,
        n_edges, nk4);

    scan_kernel<<<1, 1024, 0, stream>>>(cnt, n_nodes);

    const int nNE = (n_nodes + 31) / 32;
    const int nSC = (n_edges + 255) / 256;
    node_expand_kernel<<<nNE + nSC, 256, 0, stream>>>(
        hfeats, cfeats, Wnt, bn, Wc, bc, hc, n_nodes,
        dst, cnt, perm, n_edges, nNE);

    const int nEB = (n_edges + EB - 1) / EB;
    const int nCO = (n_nodes + 7) / 8;
    edge_kernel<<<nEB + nCO, 512, 0, stream>>>(
        efeats, src, dst, perm, Wet, be, Weot, beo, hc, k_buf, e_out, n_edges,
        nEB, cfeats, Wco, bco, c_out, n_nodes);

    node_out_kernel<<<(n_nodes + 63) / 64, 512, 0, stream>>>(
        hfeats, k_buf, Wn1t, bn1, Wn2t, bn2, h_out, n_nodes);
}